// Round 1
// baseline (335.532 us; speedup 1.0000x reference)
//
#include <hip/hip_runtime.h>
#include <math.h>

// Problem constants: B=4, N=4096, C=2048, E=64, K=2
#define T_TOKENS 16384
#define C_DIM    2048
#define N_SEQ    4096
#define E_EXP    64
#define NSLICE   4        // split-K slices
#define KSLICE   512      // C_DIM / NSLICE
#define EPB      1024     // epilogue blocks
#define GN       131072   // gate elements per split part (64*2048)

typedef __attribute__((ext_vector_type(8))) short  short8;   // 8 bf16 = 4 VGPR
typedef __attribute__((ext_vector_type(4))) float  floatx4;

// ---- exact 3-way bf16 decomposition (truncation; residuals exact) ----------
__device__ __forceinline__ void splitv(float v, ushort& h, ushort& m, ushort& l) {
    unsigned u = __float_as_uint(v);
    h = (ushort)(u >> 16);
    float f1 = v - __uint_as_float(u & 0xffff0000u);       // exact
    unsigned u1 = __float_as_uint(f1);
    m = (ushort)(u1 >> 16);
    float f2 = f1 - __uint_as_float(u1 & 0xffff0000u);     // exact
    l = (ushort)(__float_as_uint(f2) >> 16);
}

__device__ __forceinline__ void splitpack8(const float4& a, const float4& b,
                                           short8& h, short8& m, short8& l) {
    ushort hh, mm, ll;
    splitv(a.x, hh, mm, ll); h[0] = hh; m[0] = mm; l[0] = ll;
    splitv(a.y, hh, mm, ll); h[1] = hh; m[1] = mm; l[1] = ll;
    splitv(a.z, hh, mm, ll); h[2] = hh; m[2] = mm; l[2] = ll;
    splitv(a.w, hh, mm, ll); h[3] = hh; m[3] = mm; l[3] = ll;
    splitv(b.x, hh, mm, ll); h[4] = hh; m[4] = mm; l[4] = ll;
    splitv(b.y, hh, mm, ll); h[5] = hh; m[5] = mm; l[5] = ll;
    splitv(b.z, hh, mm, ll); h[6] = hh; m[6] = mm; l[6] = ll;
    splitv(b.w, hh, mm, ll); h[7] = hh; m[7] = mm; l[7] = ll;
}

// RNE split for the one-time gate_w preprocessing
__device__ __forceinline__ void split3rne(float v, ushort& h, ushort& m, ushort& l) {
    unsigned u = __float_as_uint(v);
    unsigned r = (u + 0x7fffu + ((u >> 16) & 1u)) >> 16;
    h = (ushort)r;
    float e1 = v - __uint_as_float(r << 16);
    u = __float_as_uint(e1);
    r = (u + 0x7fffu + ((u >> 16) & 1u)) >> 16;
    m = (ushort)r;
    float e2 = e1 - __uint_as_float(r << 16);
    l = (ushort)(__float_as_uint(e2) >> 16);
}

// ---------------------------------------------------------------------------
// Kernel 1 (fused): all 2048 blocks compute ctx[b][j] = dot(rc[b,:], ctx_w[j,:])
// (identical math/order to previous ctx_kernel); blocks 0..511 additionally
// split gate_w into the 3 frag-ordered bf16 parts (one element per thread —
// 512*256 = 131072 = GN exactly); block 0 zeroes the aux ticket counter.
// ---------------------------------------------------------------------------
__global__ __launch_bounds__(256) void pre_kernel(
    const float* __restrict__ rc, const float* __restrict__ ctx_w,
    const float* __restrict__ gw, float* __restrict__ ctx_out,
    ushort* __restrict__ gsp, unsigned* __restrict__ counter)
{
    if (counter != nullptr && blockIdx.x == 0 && threadIdx.x == 0) *counter = 0u;

    if (gsp != nullptr && blockIdx.x < 512) {
        const int idx  = blockIdx.x * 256 + threadIdx.x;   // 0..131071
        const int j    = idx & 7;
        const int e    = (idx >> 3) & 63;
        const int koct = idx >> 9;
        float g = gw[(size_t)e * C_DIM + koct * 8 + j];
        ushort h, m, l;
        split3rne(g, h, m, l);
        gsp[idx]          = h;
        gsp[GN + idx]     = m;
        gsp[2 * GN + idx] = l;
    }

    const int w    = threadIdx.x >> 6;
    const int lane = threadIdx.x & 63;
    const int o    = blockIdx.x * 4 + w;
    const int b    = o >> 11;
    const int j    = o & 2047;

    const float4* wr = (const float4*)(ctx_w + (size_t)j * C_DIM);
    const float4* rr = (const float4*)(rc + (size_t)b * C_DIM);
    float s = 0.f;
#pragma unroll
    for (int it = 0; it < 8; ++it) {
        float4 a = wr[it * 64 + lane];
        float4 c = rr[it * 64 + lane];
        s += a.x * c.x + a.y * c.y + a.z * c.z + a.w * c.w;
    }
#pragma unroll
    for (int off = 32; off; off >>= 1) s += __shfl_xor(s, off, 64);
    if (lane == 0) ctx_out[b * C_DIM + j] = s;
}

// ---------------------------------------------------------------------------
// Kernel 2 (fused): blocks 0..511 = barrier-free LDS-free bf16x6 MFMA split-K
// GEMM (byte-identical to previous gemm_mfma_kernel); blocks 512..575 compute
// cl[b][e] = dot(ctx[b,:], gate_w[e,:]) (the decoupled ctx@W^T term).
// ---------------------------------------------------------------------------
__global__ __launch_bounds__(256) void gemm_cl_kernel(
    const float* __restrict__ x, const ushort* __restrict__ gsp,
    const float* __restrict__ gw, const float* __restrict__ ctx,
    float* __restrict__ P, float* __restrict__ cl)
{
    if (blockIdx.x >= 128 * NSLICE) {
        const int lane = threadIdx.x & 63;
        const int pk   = (blockIdx.x - 128 * NSLICE) * 4 + (threadIdx.x >> 6); // 0..255
        const int b    = pk >> 6;
        const int e    = pk & 63;
        const float4* wr = (const float4*)(gw + (size_t)e * C_DIM);
        const float4* cr = (const float4*)(ctx + (size_t)b * C_DIM);
        float s = 0.f;
#pragma unroll
        for (int it = 0; it < 8; ++it) {
            float4 a = wr[it * 64 + lane];
            float4 c = cr[it * 64 + lane];
            s += a.x * c.x + a.y * c.y + a.z * c.z + a.w * c.w;
        }
#pragma unroll
        for (int off = 32; off; off >>= 1) s += __shfl_xor(s, off, 64);
        if (lane == 0) cl[pk] = s;
        return;
    }

    const int tid   = threadIdx.x;
    const int wv    = tid >> 6;
    const int lane  = tid & 63;
    const int l15   = lane & 15;
    const int quad  = lane >> 4;
    const int tile  = blockIdx.x & 127;     // 128 tiles x 128 tokens
    const int slice = blockIdx.x >> 7;      // 0..3
    const int tw    = tile * 128 + wv * 32; // wave token base
    const int cbase = slice * KSLICE;

    floatx4 acc[2][4];
#pragma unroll
    for (int s = 0; s < 2; ++s)
#pragma unroll
        for (int nt = 0; nt < 4; ++nt) acc[s][nt] = (floatx4){0.f, 0.f, 0.f, 0.f};

    const float* xr0 = x + (size_t)(tw + l15) * C_DIM + cbase + quad * 8;
    const float* xr1 = xr0 + (size_t)16 * C_DIM;
    const ushort* bb = gsp + ((size_t)((cbase >> 3) + quad) * 64 + l15) * 8;

#pragma unroll 2
    for (int ks = 0; ks < KSLICE / 32; ++ks) {       // 16 K=32 steps
        float4 a00 = *(const float4*)(xr0 + ks * 32);
        float4 a01 = *(const float4*)(xr0 + ks * 32 + 4);
        float4 a10 = *(const float4*)(xr1 + ks * 32);
        float4 a11 = *(const float4*)(xr1 + ks * 32 + 4);
        short8 ah0, am0, al0, ah1, am1, al1;
        splitpack8(a00, a01, ah0, am0, al0);
        splitpack8(a10, a11, ah1, am1, al1);

        const ushort* bks = bb + (size_t)ks * 4 * 64 * 8;  // 4 koct per step
#pragma unroll
        for (int nt = 0; nt < 4; ++nt) {
            const ushort* bp_ = bks + (size_t)(16 * nt) * 8;
            short8 bh = *(const short8*)(bp_);
            short8 bm = *(const short8*)(bp_ + GN);
            short8 bl = *(const short8*)(bp_ + 2 * (size_t)GN);
            acc[0][nt] = __builtin_amdgcn_mfma_f32_16x16x32_bf16(ah0, bh, acc[0][nt], 0, 0, 0);
            acc[0][nt] = __builtin_amdgcn_mfma_f32_16x16x32_bf16(ah0, bm, acc[0][nt], 0, 0, 0);
            acc[0][nt] = __builtin_amdgcn_mfma_f32_16x16x32_bf16(am0, bh, acc[0][nt], 0, 0, 0);
            acc[0][nt] = __builtin_amdgcn_mfma_f32_16x16x32_bf16(ah0, bl, acc[0][nt], 0, 0, 0);
            acc[0][nt] = __builtin_amdgcn_mfma_f32_16x16x32_bf16(al0, bh, acc[0][nt], 0, 0, 0);
            acc[0][nt] = __builtin_amdgcn_mfma_f32_16x16x32_bf16(am0, bm, acc[0][nt], 0, 0, 0);
            acc[1][nt] = __builtin_amdgcn_mfma_f32_16x16x32_bf16(ah1, bh, acc[1][nt], 0, 0, 0);
            acc[1][nt] = __builtin_amdgcn_mfma_f32_16x16x32_bf16(ah1, bm, acc[1][nt], 0, 0, 0);
            acc[1][nt] = __builtin_amdgcn_mfma_f32_16x16x32_bf16(am1, bh, acc[1][nt], 0, 0, 0);
            acc[1][nt] = __builtin_amdgcn_mfma_f32_16x16x32_bf16(ah1, bl, acc[1][nt], 0, 0, 0);
            acc[1][nt] = __builtin_amdgcn_mfma_f32_16x16x32_bf16(al1, bh, acc[1][nt], 0, 0, 0);
            acc[1][nt] = __builtin_amdgcn_mfma_f32_16x16x32_bf16(am1, bm, acc[1][nt], 0, 0, 0);
        }
    }

    // C/D layout (R6-verified): col=l15 (expert 16nt+l15), row=quad*4+r
    float* Ps = P + ((size_t)slice * T_TOKENS + tw) * E_EXP;
#pragma unroll
    for (int s = 0; s < 2; ++s)
#pragma unroll
        for (int nt = 0; nt < 4; ++nt)
#pragma unroll
            for (int r = 0; r < 4; ++r)
                Ps[(size_t)(s * 16 + quad * 4 + r) * E_EXP + 16 * nt + l15] =
                    acc[s][nt][r];
}

// ---------------------------------------------------------------------------
// Kernel 3 (fused epilogue+aux): deterministic slice sum + cl[b][e], fused
// top-2+sumexp butterfly, per-block LDS reduce -> bp[block][128]; then a
// device-scope ticket (CUB pattern: store -> threadfence -> syncthreads ->
// atomicAdd) elects the LAST block, which acquire-fences and reduces
// bp[EPB][128] -> aux loss. Eliminates the separate 1-block aux dispatch.
// ---------------------------------------------------------------------------
__global__ __launch_bounds__(256) void epilogue_aux_kernel(
    const float* __restrict__ P, const float* __restrict__ cl,
    float* __restrict__ out, float* __restrict__ bp,
    unsigned* __restrict__ counter, float* __restrict__ out_aux)
{
    __shared__ float  red[4][128];
    __shared__ float4 fred[8][32];
    __shared__ int    lastflag;

    const int tid  = threadIdx.x;
    const int wv   = tid >> 6;
    const int lane = tid & 63;
    const int t0   = blockIdx.x * (T_TOKENS / EPB);     // 16 tokens
    const float clv = cl[(t0 >> 12) * 64 + lane];       // batch = t0/4096

    float imp_acc = 0.f, cnt_acc = 0.f;

    for (int tt = 0; tt < 4; ++tt) {
        const int t = t0 + wv * 4 + tt;
        float v = clv;
#pragma unroll
        for (int s = 0; s < NSLICE; ++s)
            v += P[((size_t)s * T_TOKENS + t) * E_EXP + lane];

        const float p = expf(v);
        float v1 = v;  int i1 = lane;
        float v2 = -INFINITY; int i2 = 0x7fffffff;
        float s = p;
#pragma unroll
        for (int off = 32; off; off >>= 1) {
            float ov1 = __shfl_xor(v1, off, 64);
            int   oi1 = __shfl_xor(i1, off, 64);
            float ov2 = __shfl_xor(v2, off, 64);
            int   oi2 = __shfl_xor(i2, off, 64);
            s += __shfl_xor(s, off, 64);
            const bool aw = (ov1 < v1) || (ov1 == v1 && i1 < oi1);
            const float lv = aw ? ov1 : v1;  const int li = aw ? oi1 : i1;
            const float wv2 = aw ? v2 : ov2; const int wi = aw ? i2 : oi2;
            if (!aw) { v1 = ov1; i1 = oi1; }
            const bool sw = (wv2 < lv) || (wv2 == lv && li < wi);
            v2 = sw ? lv : wv2; i2 = sw ? li : wi;
        }

        imp_acc += p / s;
        if (lane == i1 || lane == i2) cnt_acc += 1.f;

        if (lane == 0) {
            const float e2 = expf(v2 - v1);
            out[2 * t]     = (float)i1;
            out[2 * t + 1] = (float)i2;
            out[2 * T_TOKENS + 2 * t]     = 1.f / (1.f + e2);
            out[2 * T_TOKENS + 2 * t + 1] = e2 / (1.f + e2);
        }
    }

    red[wv][lane]      = imp_acc;
    red[wv][64 + lane] = cnt_acc;
    __syncthreads();
    if (tid < 128) {
        float s = red[0][tid] + red[1][tid] + red[2][tid] + red[3][tid];
        bp[(size_t)blockIdx.x * 128 + tid] = s;
    }

    // --- ticket: elect last block (release: fence before barrier+atomic) ---
    __threadfence();
    __syncthreads();
    if (tid == 0)
        lastflag = (atomicAdd(counter, 1u) == (unsigned)(EPB - 1)) ? 1 : 0;
    __syncthreads();
    if (!lastflag) return;

    // --- last block: acquire fence, then reduce bp[EPB][128] -> aux ---
    __threadfence();
    const float4* bp4 = (const float4*)bp;
    const int c4  = tid & 31;
    const int grp = tid >> 5;                           // 0..7
    float4 s4 = make_float4(0.f, 0.f, 0.f, 0.f);
    for (int r = grp; r < EPB; r += 8) {
        float4 v = bp4[(size_t)r * 32 + c4];
        s4.x += v.x; s4.y += v.y; s4.z += v.z; s4.w += v.w;
    }
    fred[grp][c4] = s4;
    __syncthreads();

    if (tid < 32) {
        float4 t = make_float4(0.f, 0.f, 0.f, 0.f);
#pragma unroll
        for (int g = 0; g < 8; ++g) {
            float4 v = fred[g][tid];
            t.x += v.x; t.y += v.y; t.z += v.z; t.w += v.w;
        }
        fred[0][tid] = t;
    }
    __syncthreads();

    if (tid < 16) {
        float4 a = fred[0][tid];
        float4 b = fred[0][tid + 16];
        float v = a.x * b.x + a.y * b.y + a.z * b.z + a.w * b.w;
#pragma unroll
        for (int off = 8; off; off >>= 1) v += __shfl_xor(v, off, 64);
        if (tid == 0)
            out_aux[0] = (float)E_EXP * v / ((float)T_TOKENS * (float)T_TOKENS);
    }
}

// ---------------------------------------------------------------------------
// Kernel 5: parallel bp reduce -> aux loss (fallback path only)
// ---------------------------------------------------------------------------
__global__ __launch_bounds__(1024) void aux_kernel(
    const float* __restrict__ bp, int nb, float* __restrict__ out_aux)
{
    __shared__ float4 red[32][32];
    const int tid = threadIdx.x;
    const int c4  = tid & 31;
    const int grp = tid >> 5;

    const float4* bp4 = (const float4*)bp;
    float4 s = make_float4(0.f, 0.f, 0.f, 0.f);
    for (int r = grp; r < nb; r += 32) {
        float4 v = bp4[(size_t)r * 32 + c4];
        s.x += v.x; s.y += v.y; s.z += v.z; s.w += v.w;
    }
    red[grp][c4] = s;
    __syncthreads();

    if (tid < 32) {
        float4 t = make_float4(0.f, 0.f, 0.f, 0.f);
#pragma unroll
        for (int g = 0; g < 32; ++g) {
            float4 v = red[g][tid];
            t.x += v.x; t.y += v.y; t.z += v.z; t.w += v.w;
        }
        red[0][tid] = t;
    }
    __syncthreads();

    if (tid < 16) {
        float4 a = red[0][tid];
        float4 b = red[0][tid + 16];
        float v = a.x * b.x + a.y * b.y + a.z * b.z + a.w * b.w;
#pragma unroll
        for (int off = 8; off; off >>= 1) v += __shfl_xor(v, off, 64);
        if (tid == 0)
            out_aux[0] = (float)E_EXP * v / ((float)T_TOKENS * (float)T_TOKENS);
    }
}

// ---------------------------------------------------------------------------
// Fallback fused fp32 kernel (proven R5) — used only if ws too small
// ---------------------------------------------------------------------------
#define TM    64
#define FKC   64
#define FLSTR 68
__global__ __launch_bounds__(256) void router_fused_kernel(
    const float* __restrict__ x, const float* __restrict__ gate_w,
    const float* __restrict__ ctx, float* __restrict__ out,
    float* __restrict__ bp)
{
    __shared__ float xs[TM][FLSTR];
    __shared__ float gs[E_EXP][FLSTR];
    __shared__ float ls[TM][FLSTR];
    __shared__ float red[4][128];

    const int tid = threadIdx.x;
    const int eg  = tid & 15;
    const int tg  = tid >> 4;
    const int t0  = blockIdx.x * TM;
    const int b   = t0 / N_SEQ;
    const int sr  = tid >> 4;
    const int scg = tid & 15;
    const float* ctx_row = ctx + (size_t)b * C_DIM;

    float4 acc[4][4];
#pragma unroll
    for (int i = 0; i < 4; ++i)
#pragma unroll
        for (int j = 0; j < 4; ++j) acc[i][j] = make_float4(0.f, 0.f, 0.f, 0.f);

    float4 px[4], pg[4], pc;
    auto prefetch = [&](int kc) {
        const int c0 = kc * FKC + scg * 4;
        pc = *(const float4*)(ctx_row + c0);
#pragma unroll
        for (int i = 0; i < 4; ++i) {
            px[i] = *(const float4*)(x + (size_t)(t0 + sr + 16 * i) * C_DIM + c0);
            pg[i] = *(const float4*)(gate_w + (size_t)(sr + 16 * i) * C_DIM + c0);
        }
    };

    prefetch(0);
    const int NCHUNK = C_DIM / FKC;
    for (int kc = 0; kc < NCHUNK; ++kc) {
        __syncthreads();
#pragma unroll
        for (int i = 0; i < 4; ++i) {
            float4 v = px[i];
            v.x += pc.x; v.y += pc.y; v.z += pc.z; v.w += pc.w;
            *(float4*)&xs[sr + 16 * i][scg * 4] = v;
            *(float4*)&gs[sr + 16 * i][scg * 4] = pg[i];
        }
        __syncthreads();
        if (kc + 1 < NCHUNK) prefetch(kc + 1);
#pragma unroll
        for (int cc = 0; cc < FKC; cc += 4) {
            float4 xv[4], gv[4];
#pragma unroll
            for (int i = 0; i < 4; ++i) xv[i] = *(const float4*)&xs[tg + 16 * i][cc];
#pragma unroll
            for (int j = 0; j < 4; ++j) gv[j] = *(const float4*)&gs[eg + 16 * j][cc];
#pragma unroll
            for (int i = 0; i < 4; ++i)
#pragma unroll
                for (int j = 0; j < 4; ++j) {
                    acc[i][j].x = fmaf(xv[i].x, gv[j].x, acc[i][j].x);
                    acc[i][j].y = fmaf(xv[i].y, gv[j].y, acc[i][j].y);
                    acc[i][j].z = fmaf(xv[i].z, gv[j].z, acc[i][j].z);
                    acc[i][j].w = fmaf(xv[i].w, gv[j].w, acc[i][j].w);
                }
        }
    }

    __syncthreads();
#pragma unroll
    for (int i = 0; i < 4; ++i)
#pragma unroll
        for (int j = 0; j < 4; ++j)
            ls[tg + 16 * i][eg + 16 * j] =
                (acc[i][j].x + acc[i][j].y) + (acc[i][j].z + acc[i][j].w);
    __syncthreads();

    const int wv   = tid >> 6;
    const int lane = tid & 63;
    float imp_acc = 0.f, cnt_acc = 0.f;

    for (int tt = 0; tt < 16; ++tt) {
        const int tokL = wv * 16 + tt;
        const float v = ls[tokL][lane];
        const float p = expf(v);
        float v1 = v;  int i1 = lane;
        float v2 = -INFINITY; int i2 = 0x7fffffff;
        float s = p;
#pragma unroll
        for (int off = 32; off; off >>= 1) {
            float ov1 = __shfl_xor(v1, off, 64);
            int   oi1 = __shfl_xor(i1, off, 64);
            float ov2 = __shfl_xor(v2, off, 64);
            int   oi2 = __shfl_xor(i2, off, 64);
            s += __shfl_xor(s, off, 64);
            const bool aw = (ov1 < v1) || (ov1 == v1 && i1 < oi1);
            const float lv = aw ? ov1 : v1;  const int li = aw ? oi1 : i1;
            const float wv2 = aw ? v2 : ov2; const int wi = aw ? i2 : oi2;
            if (!aw) { v1 = ov1; i1 = oi1; }
            const bool sw = (wv2 < lv) || (wv2 == lv && li < wi);
            v2 = sw ? lv : wv2; i2 = sw ? li : wi;
        }
        imp_acc += p / s;
        if (lane == i1 || lane == i2) cnt_acc += 1.f;
        if (lane == 0) {
            const int t = t0 + tokL;
            const float e2 = expf(v2 - v1);
            out[2 * t]     = (float)i1;
            out[2 * t + 1] = (float)i2;
            out[2 * T_TOKENS + 2 * t]     = 1.f / (1.f + e2);
            out[2 * T_TOKENS + 2 * t + 1] = e2 / (1.f + e2);
        }
    }

    red[wv][lane]      = imp_acc;
    red[wv][64 + lane] = cnt_acc;
    __syncthreads();
    if (tid < 128) {
        float s = red[0][tid] + red[1][tid] + red[2][tid] + red[3][tid];
        bp[(size_t)blockIdx.x * 128 + tid] = s;
    }
}

extern "C" void kernel_launch(void* const* d_in, const int* in_sizes, int n_in,
                              void* d_out, int out_size, void* d_ws, size_t ws_size,
                              hipStream_t stream)
{
    (void)in_sizes; (void)n_in; (void)out_size;
    const float* x      = (const float*)d_in[0];
    const float* rc     = (const float*)d_in[1];
    const float* gate_w = (const float*)d_in[2];
    const float* ctx_w  = (const float*)d_in[3];
    float* out = (float*)d_out;

    float*  ctx = (float*)d_ws;                            // 8192 f
    float*  cl  = ctx + 8192;                              // 256 f
    float*  bp  = cl + 256;                                // EPB*128 f
    float*  P   = bp + (size_t)EPB * 128;                  // NSLICE*T*E f
    ushort* gsp = (ushort*)(P + (size_t)NSLICE * T_TOKENS * E_EXP); // 3*GN us
    unsigned* counter = (unsigned*)(gsp + (size_t)3 * GN); // 1 u32 ticket

    const size_t need =
        (8192 + 256 + (size_t)EPB * 128 + (size_t)NSLICE * T_TOKENS * E_EXP)
            * sizeof(float)
        + (size_t)3 * GN * sizeof(ushort) + sizeof(unsigned);

    if (ws_size >= need) {
        pre_kernel<<<2048, 256, 0, stream>>>(rc, ctx_w, gate_w, ctx, gsp, counter);
        gemm_cl_kernel<<<128 * NSLICE + 64, 256, 0, stream>>>(x, gsp, gate_w, ctx, P, cl);
        epilogue_aux_kernel<<<EPB, 256, 0, stream>>>(P, cl, out, bp, counter,
                                                     out + 2 * 2 * T_TOKENS);
    } else {
        pre_kernel<<<2048, 256, 0, stream>>>(rc, ctx_w, gate_w, ctx, nullptr, nullptr);
        router_fused_kernel<<<256, 256, 0, stream>>>(x, gate_w, ctx, out, bp);
        aux_kernel<<<1, 1024, 0, stream>>>(bp, 256, out + 2 * 2 * T_TOKENS);
    }
}

// Round 2
// 260.823 us; speedup vs baseline: 1.2864x; 1.2864x over previous
//
#include <hip/hip_runtime.h>
#include <math.h>

// Problem constants: B=4, N=4096, C=2048, E=64, K=2
#define T_TOKENS 16384
#define C_DIM    2048
#define N_SEQ    4096
#define E_EXP    64
#define NSLICE   8        // split-K slices (R2: 4->8 for 4 waves/SIMD occupancy)
#define KSLICE   256      // C_DIM / NSLICE
#define EPB      1024     // epilogue blocks
#define GN       131072   // gate elements per split part (64*2048)

typedef __attribute__((ext_vector_type(8))) short  short8;   // 8 bf16 = 4 VGPR
typedef __attribute__((ext_vector_type(4))) float  floatx4;

// ---- exact 3-way bf16 decomposition (truncation; residuals exact) ----------
__device__ __forceinline__ void splitv(float v, ushort& h, ushort& m, ushort& l) {
    unsigned u = __float_as_uint(v);
    h = (ushort)(u >> 16);
    float f1 = v - __uint_as_float(u & 0xffff0000u);       // exact
    unsigned u1 = __float_as_uint(f1);
    m = (ushort)(u1 >> 16);
    float f2 = f1 - __uint_as_float(u1 & 0xffff0000u);     // exact
    l = (ushort)(__float_as_uint(f2) >> 16);
}

__device__ __forceinline__ void splitpack8(const float4& a, const float4& b,
                                           short8& h, short8& m, short8& l) {
    ushort hh, mm, ll;
    splitv(a.x, hh, mm, ll); h[0] = hh; m[0] = mm; l[0] = ll;
    splitv(a.y, hh, mm, ll); h[1] = hh; m[1] = mm; l[1] = ll;
    splitv(a.z, hh, mm, ll); h[2] = hh; m[2] = mm; l[2] = ll;
    splitv(a.w, hh, mm, ll); h[3] = hh; m[3] = mm; l[3] = ll;
    splitv(b.x, hh, mm, ll); h[4] = hh; m[4] = mm; l[4] = ll;
    splitv(b.y, hh, mm, ll); h[5] = hh; m[5] = mm; l[5] = ll;
    splitv(b.z, hh, mm, ll); h[6] = hh; m[6] = mm; l[6] = ll;
    splitv(b.w, hh, mm, ll); h[7] = hh; m[7] = mm; l[7] = ll;
}

// RNE split for the one-time gate_w preprocessing
__device__ __forceinline__ void split3rne(float v, ushort& h, ushort& m, ushort& l) {
    unsigned u = __float_as_uint(v);
    unsigned r = (u + 0x7fffu + ((u >> 16) & 1u)) >> 16;
    h = (ushort)r;
    float e1 = v - __uint_as_float(r << 16);
    u = __float_as_uint(e1);
    r = (u + 0x7fffu + ((u >> 16) & 1u)) >> 16;
    m = (ushort)r;
    float e2 = e1 - __uint_as_float(r << 16);
    l = (ushort)(__float_as_uint(e2) >> 16);
}

// ---------------------------------------------------------------------------
// Kernel 1 (fused, neutral-verified R1): all 2048 blocks compute
// ctx[b][j] = dot(rc[b,:], ctx_w[j,:]); blocks 0..511 additionally split
// gate_w into the 3 frag-ordered bf16 parts (one element per thread).
// ---------------------------------------------------------------------------
__global__ __launch_bounds__(256) void pre_kernel(
    const float* __restrict__ rc, const float* __restrict__ ctx_w,
    const float* __restrict__ gw, float* __restrict__ ctx_out,
    ushort* __restrict__ gsp)
{
    if (gsp != nullptr && blockIdx.x < 512) {
        const int idx  = blockIdx.x * 256 + threadIdx.x;   // 0..131071
        const int j    = idx & 7;
        const int e    = (idx >> 3) & 63;
        const int koct = idx >> 9;
        float g = gw[(size_t)e * C_DIM + koct * 8 + j];
        ushort h, m, l;
        split3rne(g, h, m, l);
        gsp[idx]          = h;
        gsp[GN + idx]     = m;
        gsp[2 * GN + idx] = l;
    }

    const int w    = threadIdx.x >> 6;
    const int lane = threadIdx.x & 63;
    const int o    = blockIdx.x * 4 + w;
    const int b    = o >> 11;
    const int j    = o & 2047;

    const float4* wr = (const float4*)(ctx_w + (size_t)j * C_DIM);
    const float4* rr = (const float4*)(rc + (size_t)b * C_DIM);
    float s = 0.f;
#pragma unroll
    for (int it = 0; it < 8; ++it) {
        float4 a = wr[it * 64 + lane];
        float4 c = rr[it * 64 + lane];
        s += a.x * c.x + a.y * c.y + a.z * c.z + a.w * c.w;
    }
#pragma unroll
    for (int off = 32; off; off >>= 1) s += __shfl_xor(s, off, 64);
    if (lane == 0) ctx_out[b * C_DIM + j] = s;
}

// ---------------------------------------------------------------------------
// Kernel 2 (fused, neutral-verified R1): blocks 0..1023 = barrier-free
// LDS-free bf16x6 MFMA split-K GEMM (NSLICE=8 -> 4 waves/SIMD); blocks
// 1024..1087 compute cl[b][e] = dot(ctx[b,:], gate_w[e,:]).
// ---------------------------------------------------------------------------
__global__ __launch_bounds__(256) void gemm_cl_kernel(
    const float* __restrict__ x, const ushort* __restrict__ gsp,
    const float* __restrict__ gw, const float* __restrict__ ctx,
    float* __restrict__ P, float* __restrict__ cl)
{
    if (blockIdx.x >= 128 * NSLICE) {
        const int lane = threadIdx.x & 63;
        const int pk   = (blockIdx.x - 128 * NSLICE) * 4 + (threadIdx.x >> 6); // 0..255
        const int b    = pk >> 6;
        const int e    = pk & 63;
        const float4* wr = (const float4*)(gw + (size_t)e * C_DIM);
        const float4* cr = (const float4*)(ctx + (size_t)b * C_DIM);
        float s = 0.f;
#pragma unroll
        for (int it = 0; it < 8; ++it) {
            float4 a = wr[it * 64 + lane];
            float4 c = cr[it * 64 + lane];
            s += a.x * c.x + a.y * c.y + a.z * c.z + a.w * c.w;
        }
#pragma unroll
        for (int off = 32; off; off >>= 1) s += __shfl_xor(s, off, 64);
        if (lane == 0) cl[pk] = s;
        return;
    }

    const int tid   = threadIdx.x;
    const int wv    = tid >> 6;
    const int lane  = tid & 63;
    const int l15   = lane & 15;
    const int quad  = lane >> 4;
    const int tile  = blockIdx.x & 127;     // 128 tiles x 128 tokens
    const int slice = blockIdx.x >> 7;      // 0..7
    const int tw    = tile * 128 + wv * 32; // wave token base
    const int cbase = slice * KSLICE;

    floatx4 acc[2][4];
#pragma unroll
    for (int s = 0; s < 2; ++s)
#pragma unroll
        for (int nt = 0; nt < 4; ++nt) acc[s][nt] = (floatx4){0.f, 0.f, 0.f, 0.f};

    const float* xr0 = x + (size_t)(tw + l15) * C_DIM + cbase + quad * 8;
    const float* xr1 = xr0 + (size_t)16 * C_DIM;
    const ushort* bb = gsp + ((size_t)((cbase >> 3) + quad) * 64 + l15) * 8;

#pragma unroll 2
    for (int ks = 0; ks < KSLICE / 32; ++ks) {       // 8 K=32 steps
        float4 a00 = *(const float4*)(xr0 + ks * 32);
        float4 a01 = *(const float4*)(xr0 + ks * 32 + 4);
        float4 a10 = *(const float4*)(xr1 + ks * 32);
        float4 a11 = *(const float4*)(xr1 + ks * 32 + 4);
        short8 ah0, am0, al0, ah1, am1, al1;
        splitpack8(a00, a01, ah0, am0, al0);
        splitpack8(a10, a11, ah1, am1, al1);

        const ushort* bks = bb + (size_t)ks * 4 * 64 * 8;  // 4 koct per step
#pragma unroll
        for (int nt = 0; nt < 4; ++nt) {
            const ushort* bp_ = bks + (size_t)(16 * nt) * 8;
            short8 bh = *(const short8*)(bp_);
            short8 bm = *(const short8*)(bp_ + GN);
            short8 bl = *(const short8*)(bp_ + 2 * (size_t)GN);
            acc[0][nt] = __builtin_amdgcn_mfma_f32_16x16x32_bf16(ah0, bh, acc[0][nt], 0, 0, 0);
            acc[0][nt] = __builtin_amdgcn_mfma_f32_16x16x32_bf16(ah0, bm, acc[0][nt], 0, 0, 0);
            acc[0][nt] = __builtin_amdgcn_mfma_f32_16x16x32_bf16(am0, bh, acc[0][nt], 0, 0, 0);
            acc[0][nt] = __builtin_amdgcn_mfma_f32_16x16x32_bf16(ah0, bl, acc[0][nt], 0, 0, 0);
            acc[0][nt] = __builtin_amdgcn_mfma_f32_16x16x32_bf16(al0, bh, acc[0][nt], 0, 0, 0);
            acc[0][nt] = __builtin_amdgcn_mfma_f32_16x16x32_bf16(am0, bm, acc[0][nt], 0, 0, 0);
            acc[1][nt] = __builtin_amdgcn_mfma_f32_16x16x32_bf16(ah1, bh, acc[1][nt], 0, 0, 0);
            acc[1][nt] = __builtin_amdgcn_mfma_f32_16x16x32_bf16(ah1, bm, acc[1][nt], 0, 0, 0);
            acc[1][nt] = __builtin_amdgcn_mfma_f32_16x16x32_bf16(am1, bh, acc[1][nt], 0, 0, 0);
            acc[1][nt] = __builtin_amdgcn_mfma_f32_16x16x32_bf16(ah1, bl, acc[1][nt], 0, 0, 0);
            acc[1][nt] = __builtin_amdgcn_mfma_f32_16x16x32_bf16(al1, bh, acc[1][nt], 0, 0, 0);
            acc[1][nt] = __builtin_amdgcn_mfma_f32_16x16x32_bf16(am1, bm, acc[1][nt], 0, 0, 0);
        }
    }

    // C/D layout (R6-verified): col=l15 (expert 16nt+l15), row=quad*4+r
    float* Ps = P + ((size_t)slice * T_TOKENS + tw) * E_EXP;
#pragma unroll
    for (int s = 0; s < 2; ++s)
#pragma unroll
        for (int nt = 0; nt < 4; ++nt)
#pragma unroll
            for (int r = 0; r < 4; ++r)
                Ps[(size_t)(s * 16 + quad * 4 + r) * E_EXP + 16 * nt + l15] =
                    acc[s][nt][r];
}

// ---------------------------------------------------------------------------
// Kernel 3 (epilogue, restored from R0 — the R1 last-block ticket cost 90us
// in device-scope fences; kernel-boundary is the cheap fence on MI355X):
// deterministic slice sum + cl[b][e], fused top-2+sumexp butterfly,
// per-block LDS reduce -> bp[block][128].
// ---------------------------------------------------------------------------
__global__ __launch_bounds__(256) void epilogue_kernel(
    const float* __restrict__ P, const float* __restrict__ cl,
    float* __restrict__ out, float* __restrict__ bp)
{
    __shared__ float red[4][128];

    const int tid  = threadIdx.x;
    const int wv   = tid >> 6;
    const int lane = tid & 63;
    const int t0   = blockIdx.x * (T_TOKENS / EPB);     // 16 tokens
    const float clv = cl[(t0 >> 12) * 64 + lane];       // batch = t0/4096

    float imp_acc = 0.f, cnt_acc = 0.f;

    for (int tt = 0; tt < 4; ++tt) {
        const int t = t0 + wv * 4 + tt;
        float v = clv;
#pragma unroll
        for (int s = 0; s < NSLICE; ++s)
            v += P[((size_t)s * T_TOKENS + t) * E_EXP + lane];

        const float p = expf(v);
        float v1 = v;  int i1 = lane;
        float v2 = -INFINITY; int i2 = 0x7fffffff;
        float s = p;
#pragma unroll
        for (int off = 32; off; off >>= 1) {
            float ov1 = __shfl_xor(v1, off, 64);
            int   oi1 = __shfl_xor(i1, off, 64);
            float ov2 = __shfl_xor(v2, off, 64);
            int   oi2 = __shfl_xor(i2, off, 64);
            s += __shfl_xor(s, off, 64);
            const bool aw = (ov1 < v1) || (ov1 == v1 && i1 < oi1);
            const float lv = aw ? ov1 : v1;  const int li = aw ? oi1 : i1;
            const float wv2 = aw ? v2 : ov2; const int wi = aw ? i2 : oi2;
            if (!aw) { v1 = ov1; i1 = oi1; }
            const bool sw = (wv2 < lv) || (wv2 == lv && li < wi);
            v2 = sw ? lv : wv2; i2 = sw ? li : wi;
        }

        imp_acc += p / s;
        if (lane == i1 || lane == i2) cnt_acc += 1.f;

        if (lane == 0) {
            const float e2 = expf(v2 - v1);
            out[2 * t]     = (float)i1;
            out[2 * t + 1] = (float)i2;
            out[2 * T_TOKENS + 2 * t]     = 1.f / (1.f + e2);
            out[2 * T_TOKENS + 2 * t + 1] = e2 / (1.f + e2);
        }
    }

    red[wv][lane]      = imp_acc;
    red[wv][64 + lane] = cnt_acc;
    __syncthreads();
    if (tid < 128) {
        float s = red[0][tid] + red[1][tid] + red[2][tid] + red[3][tid];
        bp[(size_t)blockIdx.x * 128 + tid] = s;
    }
}

// ---------------------------------------------------------------------------
// Kernel 4: parallel bp reduce -> aux loss (proven R5)
// ---------------------------------------------------------------------------
__global__ __launch_bounds__(1024) void aux_kernel(
    const float* __restrict__ bp, int nb, float* __restrict__ out_aux)
{
    __shared__ float4 red[32][32];
    const int tid = threadIdx.x;
    const int c4  = tid & 31;
    const int grp = tid >> 5;

    const float4* bp4 = (const float4*)bp;
    float4 s = make_float4(0.f, 0.f, 0.f, 0.f);
    for (int r = grp; r < nb; r += 32) {
        float4 v = bp4[(size_t)r * 32 + c4];
        s.x += v.x; s.y += v.y; s.z += v.z; s.w += v.w;
    }
    red[grp][c4] = s;
    __syncthreads();

    if (tid < 32) {
        float4 t = make_float4(0.f, 0.f, 0.f, 0.f);
#pragma unroll
        for (int g = 0; g < 32; ++g) {
            float4 v = red[g][tid];
            t.x += v.x; t.y += v.y; t.z += v.z; t.w += v.w;
        }
        red[0][tid] = t;
    }
    __syncthreads();

    if (tid < 16) {
        float4 a = red[0][tid];
        float4 b = red[0][tid + 16];
        float v = a.x * b.x + a.y * b.y + a.z * b.z + a.w * b.w;
#pragma unroll
        for (int off = 8; off; off >>= 1) v += __shfl_xor(v, off, 64);
        if (tid == 0)
            out_aux[0] = (float)E_EXP * v / ((float)T_TOKENS * (float)T_TOKENS);
    }
}

// ---------------------------------------------------------------------------
// Fallback fused fp32 kernel (proven R5) — used only if ws too small
// ---------------------------------------------------------------------------
#define TM    64
#define FKC   64
#define FLSTR 68
__global__ __launch_bounds__(256) void router_fused_kernel(
    const float* __restrict__ x, const float* __restrict__ gate_w,
    const float* __restrict__ ctx, float* __restrict__ out,
    float* __restrict__ bp)
{
    __shared__ float xs[TM][FLSTR];
    __shared__ float gs[E_EXP][FLSTR];
    __shared__ float ls[TM][FLSTR];
    __shared__ float red[4][128];

    const int tid = threadIdx.x;
    const int eg  = tid & 15;
    const int tg  = tid >> 4;
    const int t0  = blockIdx.x * TM;
    const int b   = t0 / N_SEQ;
    const int sr  = tid >> 4;
    const int scg = tid & 15;
    const float* ctx_row = ctx + (size_t)b * C_DIM;

    float4 acc[4][4];
#pragma unroll
    for (int i = 0; i < 4; ++i)
#pragma unroll
        for (int j = 0; j < 4; ++j) acc[i][j] = make_float4(0.f, 0.f, 0.f, 0.f);

    float4 px[4], pg[4], pc;
    auto prefetch = [&](int kc) {
        const int c0 = kc * FKC + scg * 4;
        pc = *(const float4*)(ctx_row + c0);
#pragma unroll
        for (int i = 0; i < 4; ++i) {
            px[i] = *(const float4*)(x + (size_t)(t0 + sr + 16 * i) * C_DIM + c0);
            pg[i] = *(const float4*)(gate_w + (size_t)(sr + 16 * i) * C_DIM + c0);
        }
    };

    prefetch(0);
    const int NCHUNK = C_DIM / FKC;
    for (int kc = 0; kc < NCHUNK; ++kc) {
        __syncthreads();
#pragma unroll
        for (int i = 0; i < 4; ++i) {
            float4 v = px[i];
            v.x += pc.x; v.y += pc.y; v.z += pc.z; v.w += pc.w;
            *(float4*)&xs[sr + 16 * i][scg * 4] = v;
            *(float4*)&gs[sr + 16 * i][scg * 4] = pg[i];
        }
        __syncthreads();
        if (kc + 1 < NCHUNK) prefetch(kc + 1);
#pragma unroll
        for (int cc = 0; cc < FKC; cc += 4) {
            float4 xv[4], gv[4];
#pragma unroll
            for (int i = 0; i < 4; ++i) xv[i] = *(const float4*)&xs[tg + 16 * i][cc];
#pragma unroll
            for (int j = 0; j < 4; ++j) gv[j] = *(const float4*)&gs[eg + 16 * j][cc];
#pragma unroll
            for (int i = 0; i < 4; ++i)
#pragma unroll
                for (int j = 0; j < 4; ++j) {
                    acc[i][j].x = fmaf(xv[i].x, gv[j].x, acc[i][j].x);
                    acc[i][j].y = fmaf(xv[i].y, gv[j].y, acc[i][j].y);
                    acc[i][j].z = fmaf(xv[i].z, gv[j].z, acc[i][j].z);
                    acc[i][j].w = fmaf(xv[i].w, gv[j].w, acc[i][j].w);
                }
        }
    }

    __syncthreads();
#pragma unroll
    for (int i = 0; i < 4; ++i)
#pragma unroll
        for (int j = 0; j < 4; ++j)
            ls[tg + 16 * i][eg + 16 * j] =
                (acc[i][j].x + acc[i][j].y) + (acc[i][j].z + acc[i][j].w);
    __syncthreads();

    const int wv   = tid >> 6;
    const int lane = tid & 63;
    float imp_acc = 0.f, cnt_acc = 0.f;

    for (int tt = 0; tt < 16; ++tt) {
        const int tokL = wv * 16 + tt;
        const float v = ls[tokL][lane];
        const float p = expf(v);
        float v1 = v;  int i1 = lane;
        float v2 = -INFINITY; int i2 = 0x7fffffff;
        float s = p;
#pragma unroll
        for (int off = 32; off; off >>= 1) {
            float ov1 = __shfl_xor(v1, off, 64);
            int   oi1 = __shfl_xor(i1, off, 64);
            float ov2 = __shfl_xor(v2, off, 64);
            int   oi2 = __shfl_xor(i2, off, 64);
            s += __shfl_xor(s, off, 64);
            const bool aw = (ov1 < v1) || (ov1 == v1 && i1 < oi1);
            const float lv = aw ? ov1 : v1;  const int li = aw ? oi1 : i1;
            const float wv2 = aw ? v2 : ov2; const int wi = aw ? i2 : oi2;
            if (!aw) { v1 = ov1; i1 = oi1; }
            const bool sw = (wv2 < lv) || (wv2 == lv && li < wi);
            v2 = sw ? lv : wv2; i2 = sw ? li : wi;
        }
        imp_acc += p / s;
        if (lane == i1 || lane == i2) cnt_acc += 1.f;
        if (lane == 0) {
            const int t = t0 + tokL;
            const float e2 = expf(v2 - v1);
            out[2 * t]     = (float)i1;
            out[2 * t + 1] = (float)i2;
            out[2 * T_TOKENS + 2 * t]     = 1.f / (1.f + e2);
            out[2 * T_TOKENS + 2 * t + 1] = e2 / (1.f + e2);
        }
    }

    red[wv][lane]      = imp_acc;
    red[wv][64 + lane] = cnt_acc;
    __syncthreads();
    if (tid < 128) {
        float s = red[0][tid] + red[1][tid] + red[2][tid] + red[3][tid];
        bp[(size_t)blockIdx.x * 128 + tid] = s;
    }
}

extern "C" void kernel_launch(void* const* d_in, const int* in_sizes, int n_in,
                              void* d_out, int out_size, void* d_ws, size_t ws_size,
                              hipStream_t stream)
{
    (void)in_sizes; (void)n_in; (void)out_size;
    const float* x      = (const float*)d_in[0];
    const float* rc     = (const float*)d_in[1];
    const float* gate_w = (const float*)d_in[2];
    const float* ctx_w  = (const float*)d_in[3];
    float* out = (float*)d_out;

    float*  ctx = (float*)d_ws;                            // 8192 f
    float*  cl  = ctx + 8192;                              // 256 f
    float*  bp  = cl + 256;                                // EPB*128 f
    float*  P   = bp + (size_t)EPB * 128;                  // NSLICE*T*E f
    ushort* gsp = (ushort*)(P + (size_t)NSLICE * T_TOKENS * E_EXP); // 3*GN us

    const size_t need =
        (8192 + 256 + (size_t)EPB * 128 + (size_t)NSLICE * T_TOKENS * E_EXP)
            * sizeof(float)
        + (size_t)3 * GN * sizeof(ushort);

    if (ws_size >= need) {
        pre_kernel<<<2048, 256, 0, stream>>>(rc, ctx_w, gate_w, ctx, gsp);
        gemm_cl_kernel<<<128 * NSLICE + 64, 256, 0, stream>>>(x, gsp, gate_w, ctx, P, cl);
        epilogue_kernel<<<EPB, 256, 0, stream>>>(P, cl, out, bp);
        aux_kernel<<<1, 1024, 0, stream>>>(bp, EPB, out + 2 * 2 * T_TOKENS);
    } else {
        pre_kernel<<<2048, 256, 0, stream>>>(rc, ctx_w, gate_w, ctx, nullptr);
        router_fused_kernel<<<256, 256, 0, stream>>>(x, gate_w, ctx, out, bp);
        aux_kernel<<<1, 1024, 0, stream>>>(bp, 256, out + 2 * 2 * T_TOKENS);
    }
}

// Round 3
// 249.227 us; speedup vs baseline: 1.3463x; 1.0465x over previous
//
#include <hip/hip_runtime.h>
#include <math.h>

// Problem constants: B=4, N=4096, C=2048, E=64, K=2
#define T_TOKENS 16384
#define C_DIM    2048
#define N_SEQ    4096
#define E_EXP    64
#define NSLICE   4        // split-K slices (R2: 8 regressed; 4 proven)
#define KSLICE   512      // C_DIM / NSLICE
#define EPB      1024     // epilogue blocks
#define GN       131072   // gate elements per split part (64*2048)

typedef __attribute__((ext_vector_type(8))) short  short8;   // 8 bf16 = 4 VGPR
typedef __attribute__((ext_vector_type(4))) float  floatx4;

// ---- exact 3-way bf16 decomposition (truncation; residuals exact) ----------
__device__ __forceinline__ void splitv(float v, ushort& h, ushort& m, ushort& l) {
    unsigned u = __float_as_uint(v);
    h = (ushort)(u >> 16);
    float f1 = v - __uint_as_float(u & 0xffff0000u);       // exact
    unsigned u1 = __float_as_uint(f1);
    m = (ushort)(u1 >> 16);
    float f2 = f1 - __uint_as_float(u1 & 0xffff0000u);     // exact
    l = (ushort)(__float_as_uint(f2) >> 16);
}

__device__ __forceinline__ void splitpack8(const float4& a, const float4& b,
                                           short8& h, short8& m, short8& l) {
    ushort hh, mm, ll;
    splitv(a.x, hh, mm, ll); h[0] = hh; m[0] = mm; l[0] = ll;
    splitv(a.y, hh, mm, ll); h[1] = hh; m[1] = mm; l[1] = ll;
    splitv(a.z, hh, mm, ll); h[2] = hh; m[2] = mm; l[2] = ll;
    splitv(a.w, hh, mm, ll); h[3] = hh; m[3] = mm; l[3] = ll;
    splitv(b.x, hh, mm, ll); h[4] = hh; m[4] = mm; l[4] = ll;
    splitv(b.y, hh, mm, ll); h[5] = hh; m[5] = mm; l[5] = ll;
    splitv(b.z, hh, mm, ll); h[6] = hh; m[6] = mm; l[6] = ll;
    splitv(b.w, hh, mm, ll); h[7] = hh; m[7] = mm; l[7] = ll;
}

// RNE split for the one-time gate_w preprocessing
__device__ __forceinline__ void split3rne(float v, ushort& h, ushort& m, ushort& l) {
    unsigned u = __float_as_uint(v);
    unsigned r = (u + 0x7fffu + ((u >> 16) & 1u)) >> 16;
    h = (ushort)r;
    float e1 = v - __uint_as_float(r << 16);
    u = __float_as_uint(e1);
    r = (u + 0x7fffu + ((u >> 16) & 1u)) >> 16;
    m = (ushort)r;
    float e2 = e1 - __uint_as_float(r << 16);
    l = (ushort)(__float_as_uint(e2) >> 16);
}

// ---------------------------------------------------------------------------
// Kernel 1 (fused, neutral-verified R1): all 2048 blocks compute
// ctx[b][j] = dot(rc[b,:], ctx_w[j,:]); blocks 0..511 additionally split
// gate_w into the 3 frag-ordered bf16 parts (one element per thread).
// ---------------------------------------------------------------------------
__global__ __launch_bounds__(256) void pre_kernel(
    const float* __restrict__ rc, const float* __restrict__ ctx_w,
    const float* __restrict__ gw, float* __restrict__ ctx_out,
    ushort* __restrict__ gsp)
{
    if (gsp != nullptr && blockIdx.x < 512) {
        const int idx  = blockIdx.x * 256 + threadIdx.x;   // 0..131071
        const int j    = idx & 7;
        const int e    = (idx >> 3) & 63;
        const int koct = idx >> 9;
        float g = gw[(size_t)e * C_DIM + koct * 8 + j];
        ushort h, m, l;
        split3rne(g, h, m, l);
        gsp[idx]          = h;
        gsp[GN + idx]     = m;
        gsp[2 * GN + idx] = l;
    }

    const int w    = threadIdx.x >> 6;
    const int lane = threadIdx.x & 63;
    const int o    = blockIdx.x * 4 + w;
    const int b    = o >> 11;
    const int j    = o & 2047;

    const float4* wr = (const float4*)(ctx_w + (size_t)j * C_DIM);
    const float4* rr = (const float4*)(rc + (size_t)b * C_DIM);
    float s = 0.f;
#pragma unroll
    for (int it = 0; it < 8; ++it) {
        float4 a = wr[it * 64 + lane];
        float4 c = rr[it * 64 + lane];
        s += a.x * c.x + a.y * c.y + a.z * c.z + a.w * c.w;
    }
#pragma unroll
    for (int off = 32; off; off >>= 1) s += __shfl_xor(s, off, 64);
    if (lane == 0) ctx_out[b * C_DIM + j] = s;
}

// ---------------------------------------------------------------------------
// Kernel 2: blocks 0..511 = barrier-free LDS-free bf16x6 MFMA split-K GEMM.
// R3 change: explicit next-iteration A-prefetch (issue ks+1's 4 float4 at
// iteration top, consume next iteration) so HBM latency hides under the
// splitpack VALU + MFMA of the current step. R2 counters (MfmaUtil 11%,
// VALUBusy 10%, HBM 15%, occupancy-insensitive) proved per-wave
// latency-bound, not occupancy-bound. Blocks 512..575 compute cl[b][e].
// ---------------------------------------------------------------------------
__global__ __launch_bounds__(256) void gemm_cl_kernel(
    const float* __restrict__ x, const ushort* __restrict__ gsp,
    const float* __restrict__ gw, const float* __restrict__ ctx,
    float* __restrict__ P, float* __restrict__ cl)
{
    if (blockIdx.x >= 128 * NSLICE) {
        const int lane = threadIdx.x & 63;
        const int pk   = (blockIdx.x - 128 * NSLICE) * 4 + (threadIdx.x >> 6); // 0..255
        const int b    = pk >> 6;
        const int e    = pk & 63;
        const float4* wr = (const float4*)(gw + (size_t)e * C_DIM);
        const float4* cr = (const float4*)(ctx + (size_t)b * C_DIM);
        float s = 0.f;
#pragma unroll
        for (int it = 0; it < 8; ++it) {
            float4 a = wr[it * 64 + lane];
            float4 c = cr[it * 64 + lane];
            s += a.x * c.x + a.y * c.y + a.z * c.z + a.w * c.w;
        }
#pragma unroll
        for (int off = 32; off; off >>= 1) s += __shfl_xor(s, off, 64);
        if (lane == 0) cl[pk] = s;
        return;
    }

    const int tid   = threadIdx.x;
    const int wv    = tid >> 6;
    const int lane  = tid & 63;
    const int l15   = lane & 15;
    const int quad  = lane >> 4;
    const int tile  = blockIdx.x & 127;     // 128 tiles x 128 tokens
    const int slice = blockIdx.x >> 7;      // 0..3
    const int tw    = tile * 128 + wv * 32; // wave token base
    const int cbase = slice * KSLICE;

    floatx4 acc[2][4];
#pragma unroll
    for (int s = 0; s < 2; ++s)
#pragma unroll
        for (int nt = 0; nt < 4; ++nt) acc[s][nt] = (floatx4){0.f, 0.f, 0.f, 0.f};

    const float* xr0 = x + (size_t)(tw + l15) * C_DIM + cbase + quad * 8;
    const float* xr1 = xr0 + (size_t)16 * C_DIM;
    const ushort* bb = gsp + ((size_t)((cbase >> 3) + quad) * 64 + l15) * 8;

    const int NKS = KSLICE / 32;            // 16 K=32 steps

    // prologue: issue ks=0 A-loads
    float4 a00 = *(const float4*)(xr0);
    float4 a01 = *(const float4*)(xr0 + 4);
    float4 a10 = *(const float4*)(xr1);
    float4 a11 = *(const float4*)(xr1 + 4);

#pragma unroll 2
    for (int ks = 0; ks < NKS; ++ks) {
        // --- issue next-iteration A-loads FIRST (T14: issue-early) ---
        // last iteration wraps to 0: always in-bounds, result discarded
        const int nk = (ks + 1 < NKS) ? (ks + 1) : 0;
        float4 n00 = *(const float4*)(xr0 + nk * 32);
        float4 n01 = *(const float4*)(xr0 + nk * 32 + 4);
        float4 n10 = *(const float4*)(xr1 + nk * 32);
        float4 n11 = *(const float4*)(xr1 + nk * 32 + 4);

        // --- consume current A (loaded last iteration / prologue) ---
        short8 ah0, am0, al0, ah1, am1, al1;
        splitpack8(a00, a01, ah0, am0, al0);
        splitpack8(a10, a11, ah1, am1, al1);

        const ushort* bks = bb + (size_t)ks * 4 * 64 * 8;  // 4 koct per step
#pragma unroll
        for (int nt = 0; nt < 4; ++nt) {
            const ushort* bp_ = bks + (size_t)(16 * nt) * 8;
            short8 bh = *(const short8*)(bp_);
            short8 bm = *(const short8*)(bp_ + GN);
            short8 bl = *(const short8*)(bp_ + 2 * (size_t)GN);
            acc[0][nt] = __builtin_amdgcn_mfma_f32_16x16x32_bf16(ah0, bh, acc[0][nt], 0, 0, 0);
            acc[0][nt] = __builtin_amdgcn_mfma_f32_16x16x32_bf16(ah0, bm, acc[0][nt], 0, 0, 0);
            acc[0][nt] = __builtin_amdgcn_mfma_f32_16x16x32_bf16(am0, bh, acc[0][nt], 0, 0, 0);
            acc[0][nt] = __builtin_amdgcn_mfma_f32_16x16x32_bf16(ah0, bl, acc[0][nt], 0, 0, 0);
            acc[0][nt] = __builtin_amdgcn_mfma_f32_16x16x32_bf16(al0, bh, acc[0][nt], 0, 0, 0);
            acc[0][nt] = __builtin_amdgcn_mfma_f32_16x16x32_bf16(am0, bm, acc[0][nt], 0, 0, 0);
            acc[1][nt] = __builtin_amdgcn_mfma_f32_16x16x32_bf16(ah1, bh, acc[1][nt], 0, 0, 0);
            acc[1][nt] = __builtin_amdgcn_mfma_f32_16x16x32_bf16(ah1, bm, acc[1][nt], 0, 0, 0);
            acc[1][nt] = __builtin_amdgcn_mfma_f32_16x16x32_bf16(am1, bh, acc[1][nt], 0, 0, 0);
            acc[1][nt] = __builtin_amdgcn_mfma_f32_16x16x32_bf16(ah1, bl, acc[1][nt], 0, 0, 0);
            acc[1][nt] = __builtin_amdgcn_mfma_f32_16x16x32_bf16(al1, bh, acc[1][nt], 0, 0, 0);
            acc[1][nt] = __builtin_amdgcn_mfma_f32_16x16x32_bf16(am1, bm, acc[1][nt], 0, 0, 0);
        }

        a00 = n00; a01 = n01; a10 = n10; a11 = n11;
    }

    // C/D layout (R6-verified): col=l15 (expert 16nt+l15), row=quad*4+r
    float* Ps = P + ((size_t)slice * T_TOKENS + tw) * E_EXP;
#pragma unroll
    for (int s = 0; s < 2; ++s)
#pragma unroll
        for (int nt = 0; nt < 4; ++nt)
#pragma unroll
            for (int r = 0; r < 4; ++r)
                Ps[(size_t)(s * 16 + quad * 4 + r) * E_EXP + 16 * nt + l15] =
                    acc[s][nt][r];
}

// ---------------------------------------------------------------------------
// Kernel 3 (epilogue, proven): deterministic slice sum + cl[b][e], fused
// top-2+sumexp butterfly, per-block LDS reduce -> bp[block][128].
// ---------------------------------------------------------------------------
__global__ __launch_bounds__(256) void epilogue_kernel(
    const float* __restrict__ P, const float* __restrict__ cl,
    float* __restrict__ out, float* __restrict__ bp)
{
    __shared__ float red[4][128];

    const int tid  = threadIdx.x;
    const int wv   = tid >> 6;
    const int lane = tid & 63;
    const int t0   = blockIdx.x * (T_TOKENS / EPB);     // 16 tokens
    const float clv = cl[(t0 >> 12) * 64 + lane];       // batch = t0/4096

    float imp_acc = 0.f, cnt_acc = 0.f;

    for (int tt = 0; tt < 4; ++tt) {
        const int t = t0 + wv * 4 + tt;
        float v = clv;
#pragma unroll
        for (int s = 0; s < NSLICE; ++s)
            v += P[((size_t)s * T_TOKENS + t) * E_EXP + lane];

        const float p = expf(v);
        float v1 = v;  int i1 = lane;
        float v2 = -INFINITY; int i2 = 0x7fffffff;
        float s = p;
#pragma unroll
        for (int off = 32; off; off >>= 1) {
            float ov1 = __shfl_xor(v1, off, 64);
            int   oi1 = __shfl_xor(i1, off, 64);
            float ov2 = __shfl_xor(v2, off, 64);
            int   oi2 = __shfl_xor(i2, off, 64);
            s += __shfl_xor(s, off, 64);
            const bool aw = (ov1 < v1) || (ov1 == v1 && i1 < oi1);
            const float lv = aw ? ov1 : v1;  const int li = aw ? oi1 : i1;
            const float wv2 = aw ? v2 : ov2; const int wi = aw ? i2 : oi2;
            if (!aw) { v1 = ov1; i1 = oi1; }
            const bool sw = (wv2 < lv) || (wv2 == lv && li < wi);
            v2 = sw ? lv : wv2; i2 = sw ? li : wi;
        }

        imp_acc += p / s;
        if (lane == i1 || lane == i2) cnt_acc += 1.f;

        if (lane == 0) {
            const float e2 = expf(v2 - v1);
            out[2 * t]     = (float)i1;
            out[2 * t + 1] = (float)i2;
            out[2 * T_TOKENS + 2 * t]     = 1.f / (1.f + e2);
            out[2 * T_TOKENS + 2 * t + 1] = e2 / (1.f + e2);
        }
    }

    red[wv][lane]      = imp_acc;
    red[wv][64 + lane] = cnt_acc;
    __syncthreads();
    if (tid < 128) {
        float s = red[0][tid] + red[1][tid] + red[2][tid] + red[3][tid];
        bp[(size_t)blockIdx.x * 128 + tid] = s;
    }
}

// ---------------------------------------------------------------------------
// Kernel 4: parallel bp reduce -> aux loss (proven R5)
// ---------------------------------------------------------------------------
__global__ __launch_bounds__(1024) void aux_kernel(
    const float* __restrict__ bp, int nb, float* __restrict__ out_aux)
{
    __shared__ float4 red[32][32];
    const int tid = threadIdx.x;
    const int c4  = tid & 31;
    const int grp = tid >> 5;

    const float4* bp4 = (const float4*)bp;
    float4 s = make_float4(0.f, 0.f, 0.f, 0.f);
    for (int r = grp; r < nb; r += 32) {
        float4 v = bp4[(size_t)r * 32 + c4];
        s.x += v.x; s.y += v.y; s.z += v.z; s.w += v.w;
    }
    red[grp][c4] = s;
    __syncthreads();

    if (tid < 32) {
        float4 t = make_float4(0.f, 0.f, 0.f, 0.f);
#pragma unroll
        for (int g = 0; g < 32; ++g) {
            float4 v = red[g][tid];
            t.x += v.x; t.y += v.y; t.z += v.z; t.w += v.w;
        }
        red[0][tid] = t;
    }
    __syncthreads();

    if (tid < 16) {
        float4 a = red[0][tid];
        float4 b = red[0][tid + 16];
        float v = a.x * b.x + a.y * b.y + a.z * b.z + a.w * b.w;
#pragma unroll
        for (int off = 8; off; off >>= 1) v += __shfl_xor(v, off, 64);
        if (tid == 0)
            out_aux[0] = (float)E_EXP * v / ((float)T_TOKENS * (float)T_TOKENS);
    }
}

// ---------------------------------------------------------------------------
// Fallback fused fp32 kernel (proven R5) — used only if ws too small
// ---------------------------------------------------------------------------
#define TM    64
#define FKC   64
#define FLSTR 68
__global__ __launch_bounds__(256) void router_fused_kernel(
    const float* __restrict__ x, const float* __restrict__ gate_w,
    const float* __restrict__ ctx, float* __restrict__ out,
    float* __restrict__ bp)
{
    __shared__ float xs[TM][FLSTR];
    __shared__ float gs[E_EXP][FLSTR];
    __shared__ float ls[TM][FLSTR];
    __shared__ float red[4][128];

    const int tid = threadIdx.x;
    const int eg  = tid & 15;
    const int tg  = tid >> 4;
    const int t0  = blockIdx.x * TM;
    const int b   = t0 / N_SEQ;
    const int sr  = tid >> 4;
    const int scg = tid & 15;
    const float* ctx_row = ctx + (size_t)b * C_DIM;

    float4 acc[4][4];
#pragma unroll
    for (int i = 0; i < 4; ++i)
#pragma unroll
        for (int j = 0; j < 4; ++j) acc[i][j] = make_float4(0.f, 0.f, 0.f, 0.f);

    float4 px[4], pg[4], pc;
    auto prefetch = [&](int kc) {
        const int c0 = kc * FKC + scg * 4;
        pc = *(const float4*)(ctx_row + c0);
#pragma unroll
        for (int i = 0; i < 4; ++i) {
            px[i] = *(const float4*)(x + (size_t)(t0 + sr + 16 * i) * C_DIM + c0);
            pg[i] = *(const float4*)(gate_w + (size_t)(sr + 16 * i) * C_DIM + c0);
        }
    };

    prefetch(0);
    const int NCHUNK = C_DIM / FKC;
    for (int kc = 0; kc < NCHUNK; ++kc) {
        __syncthreads();
#pragma unroll
        for (int i = 0; i < 4; ++i) {
            float4 v = px[i];
            v.x += pc.x; v.y += pc.y; v.z += pc.z; v.w += pc.w;
            *(float4*)&xs[sr + 16 * i][scg * 4] = v;
            *(float4*)&gs[sr + 16 * i][scg * 4] = pg[i];
        }
        __syncthreads();
        if (kc + 1 < NCHUNK) prefetch(kc + 1);
#pragma unroll
        for (int cc = 0; cc < FKC; cc += 4) {
            float4 xv[4], gv[4];
#pragma unroll
            for (int i = 0; i < 4; ++i) xv[i] = *(const float4*)&xs[tg + 16 * i][cc];
#pragma unroll
            for (int j = 0; j < 4; ++j) gv[j] = *(const float4*)&gs[eg + 16 * j][cc];
#pragma unroll
            for (int i = 0; i < 4; ++i)
#pragma unroll
                for (int j = 0; j < 4; ++j) {
                    acc[i][j].x = fmaf(xv[i].x, gv[j].x, acc[i][j].x);
                    acc[i][j].y = fmaf(xv[i].y, gv[j].y, acc[i][j].y);
                    acc[i][j].z = fmaf(xv[i].z, gv[j].z, acc[i][j].z);
                    acc[i][j].w = fmaf(xv[i].w, gv[j].w, acc[i][j].w);
                }
        }
    }

    __syncthreads();
#pragma unroll
    for (int i = 0; i < 4; ++i)
#pragma unroll
        for (int j = 0; j < 4; ++j)
            ls[tg + 16 * i][eg + 16 * j] =
                (acc[i][j].x + acc[i][j].y) + (acc[i][j].z + acc[i][j].w);
    __syncthreads();

    const int wv   = tid >> 6;
    const int lane = tid & 63;
    float imp_acc = 0.f, cnt_acc = 0.f;

    for (int tt = 0; tt < 16; ++tt) {
        const int tokL = wv * 16 + tt;
        const float v = ls[tokL][lane];
        const float p = expf(v);
        float v1 = v;  int i1 = lane;
        float v2 = -INFINITY; int i2 = 0x7fffffff;
        float s = p;
#pragma unroll
        for (int off = 32; off; off >>= 1) {
            float ov1 = __shfl_xor(v1, off, 64);
            int   oi1 = __shfl_xor(i1, off, 64);
            float ov2 = __shfl_xor(v2, off, 64);
            int   oi2 = __shfl_xor(i2, off, 64);
            s += __shfl_xor(s, off, 64);
            const bool aw = (ov1 < v1) || (ov1 == v1 && i1 < oi1);
            const float lv = aw ? ov1 : v1;  const int li = aw ? oi1 : i1;
            const float wv2 = aw ? v2 : ov2; const int wi = aw ? i2 : oi2;
            if (!aw) { v1 = ov1; i1 = oi1; }
            const bool sw = (wv2 < lv) || (wv2 == lv && li < wi);
            v2 = sw ? lv : wv2; i2 = sw ? li : wi;
        }
        imp_acc += p / s;
        if (lane == i1 || lane == i2) cnt_acc += 1.f;
        if (lane == 0) {
            const int t = t0 + tokL;
            const float e2 = expf(v2 - v1);
            out[2 * t]     = (float)i1;
            out[2 * t + 1] = (float)i2;
            out[2 * T_TOKENS + 2 * t]     = 1.f / (1.f + e2);
            out[2 * T_TOKENS + 2 * t + 1] = e2 / (1.f + e2);
        }
    }

    red[wv][lane]      = imp_acc;
    red[wv][64 + lane] = cnt_acc;
    __syncthreads();
    if (tid < 128) {
        float s = red[0][tid] + red[1][tid] + red[2][tid] + red[3][tid];
        bp[(size_t)blockIdx.x * 128 + tid] = s;
    }
}

extern "C" void kernel_launch(void* const* d_in, const int* in_sizes, int n_in,
                              void* d_out, int out_size, void* d_ws, size_t ws_size,
                              hipStream_t stream)
{
    (void)in_sizes; (void)n_in; (void)out_size;
    const float* x      = (const float*)d_in[0];
    const float* rc     = (const float*)d_in[1];
    const float* gate_w = (const float*)d_in[2];
    const float* ctx_w  = (const float*)d_in[3];
    float* out = (float*)d_out;

    float*  ctx = (float*)d_ws;                            // 8192 f
    float*  cl  = ctx + 8192;                              // 256 f
    float*  bp  = cl + 256;                                // EPB*128 f
    float*  P   = bp + (size_t)EPB * 128;                  // NSLICE*T*E f
    ushort* gsp = (ushort*)(P + (size_t)NSLICE * T_TOKENS * E_EXP); // 3*GN us

    const size_t need =
        (8192 + 256 + (size_t)EPB * 128 + (size_t)NSLICE * T_TOKENS * E_EXP)
            * sizeof(float)
        + (size_t)3 * GN * sizeof(ushort);

    if (ws_size >= need) {
        pre_kernel<<<2048, 256, 0, stream>>>(rc, ctx_w, gate_w, ctx, gsp);
        gemm_cl_kernel<<<128 * NSLICE + 64, 256, 0, stream>>>(x, gsp, gate_w, ctx, P, cl);
        epilogue_kernel<<<EPB, 256, 0, stream>>>(P, cl, out, bp);
        aux_kernel<<<1, 1024, 0, stream>>>(bp, EPB, out + 2 * 2 * T_TOKENS);
    } else {
        pre_kernel<<<2048, 256, 0, stream>>>(rc, ctx_w, gate_w, ctx, nullptr);
        router_fused_kernel<<<256, 256, 0, stream>>>(x, gate_w, ctx, out, bp);
        aux_kernel<<<1, 1024, 0, stream>>>(bp, 256, out + 2 * 2 * T_TOKENS);
    }
}

// Round 4
// 246.151 us; speedup vs baseline: 1.3631x; 1.0125x over previous
//
#include <hip/hip_runtime.h>
#include <math.h>

// Problem constants: B=4, N=4096, C=2048, E=64, K=2
#define T_TOKENS 16384
#define C_DIM    2048
#define N_SEQ    4096
#define E_EXP    64
#define NSLICE   4        // split-K slices (R2: 8 regressed; 4 proven)
#define KSLICE   512      // C_DIM / NSLICE
#define EPB      1024     // epilogue blocks
#define GN       131072   // gate elements per split part (64*2048)

typedef __attribute__((ext_vector_type(8))) short  short8;   // 8 bf16 = 4 VGPR
typedef __attribute__((ext_vector_type(4))) float  floatx4;

// ---- exact 3-way bf16 decomposition (truncation; residuals exact) ----------
__device__ __forceinline__ void splitv(float v, ushort& h, ushort& m, ushort& l) {
    unsigned u = __float_as_uint(v);
    h = (ushort)(u >> 16);
    float f1 = v - __uint_as_float(u & 0xffff0000u);       // exact
    unsigned u1 = __float_as_uint(f1);
    m = (ushort)(u1 >> 16);
    float f2 = f1 - __uint_as_float(u1 & 0xffff0000u);     // exact
    l = (ushort)(__float_as_uint(f2) >> 16);
}

__device__ __forceinline__ void splitpack8(const float4& a, const float4& b,
                                           short8& h, short8& m, short8& l) {
    ushort hh, mm, ll;
    splitv(a.x, hh, mm, ll); h[0] = hh; m[0] = mm; l[0] = ll;
    splitv(a.y, hh, mm, ll); h[1] = hh; m[1] = mm; l[1] = ll;
    splitv(a.z, hh, mm, ll); h[2] = hh; m[2] = mm; l[2] = ll;
    splitv(a.w, hh, mm, ll); h[3] = hh; m[3] = mm; l[3] = ll;
    splitv(b.x, hh, mm, ll); h[4] = hh; m[4] = mm; l[4] = ll;
    splitv(b.y, hh, mm, ll); h[5] = hh; m[5] = mm; l[5] = ll;
    splitv(b.z, hh, mm, ll); h[6] = hh; m[6] = mm; l[6] = ll;
    splitv(b.w, hh, mm, ll); h[7] = hh; m[7] = mm; l[7] = ll;
}

// RNE split for the one-time gate_w preprocessing
__device__ __forceinline__ void split3rne(float v, ushort& h, ushort& m, ushort& l) {
    unsigned u = __float_as_uint(v);
    unsigned r = (u + 0x7fffu + ((u >> 16) & 1u)) >> 16;
    h = (ushort)r;
    float e1 = v - __uint_as_float(r << 16);
    u = __float_as_uint(e1);
    r = (u + 0x7fffu + ((u >> 16) & 1u)) >> 16;
    m = (ushort)r;
    float e2 = e1 - __uint_as_float(r << 16);
    l = (ushort)(__float_as_uint(e2) >> 16);
}

// ---------------------------------------------------------------------------
// Kernel 1 (R4 restructure): 512 blocks. Each wave computes ctx[b][j] for ONE
// j and ALL 4 batches (ctx_w row read once: 16.8 MB total vs 67 MB before;
// rc rows L1-resident). Per-(b,j) FMA order and shuffle-reduce identical to
// the old kernel -> bit-identical ctx. All blocks also do the gsp split
// (512*256 = GN exactly).
// ---------------------------------------------------------------------------
__global__ __launch_bounds__(256, 2) void pre_kernel(
    const float* __restrict__ rc, const float* __restrict__ ctx_w,
    const float* __restrict__ gw, float* __restrict__ ctx_out,
    ushort* __restrict__ gsp)
{
    if (gsp != nullptr) {
        const int idx  = blockIdx.x * 256 + threadIdx.x;   // 0..131071
        const int j    = idx & 7;
        const int e    = (idx >> 3) & 63;
        const int koct = idx >> 9;
        float g = gw[(size_t)e * C_DIM + koct * 8 + j];
        ushort h, m, l;
        split3rne(g, h, m, l);
        gsp[idx]          = h;
        gsp[GN + idx]     = m;
        gsp[2 * GN + idx] = l;
    }

    const int w    = threadIdx.x >> 6;
    const int lane = threadIdx.x & 63;
    const int j    = blockIdx.x * 4 + w;                   // 0..2047

    const float4* wr = (const float4*)(ctx_w + (size_t)j * C_DIM);
    const float4* r0 = (const float4*)(rc);
    const float4* r1 = (const float4*)(rc + C_DIM);
    const float4* r2 = (const float4*)(rc + 2 * C_DIM);
    const float4* r3 = (const float4*)(rc + 3 * C_DIM);

    float s0 = 0.f, s1 = 0.f, s2 = 0.f, s3 = 0.f;
#pragma unroll
    for (int it = 0; it < 8; ++it) {
        float4 a  = wr[it * 64 + lane];
        float4 c0 = r0[it * 64 + lane];
        float4 c1 = r1[it * 64 + lane];
        float4 c2 = r2[it * 64 + lane];
        float4 c3 = r3[it * 64 + lane];
        s0 += a.x * c0.x + a.y * c0.y + a.z * c0.z + a.w * c0.w;
        s1 += a.x * c1.x + a.y * c1.y + a.z * c1.z + a.w * c1.w;
        s2 += a.x * c2.x + a.y * c2.y + a.z * c2.z + a.w * c2.w;
        s3 += a.x * c3.x + a.y * c3.y + a.z * c3.z + a.w * c3.w;
    }
#pragma unroll
    for (int off = 32; off; off >>= 1) {
        s0 += __shfl_xor(s0, off, 64);
        s1 += __shfl_xor(s1, off, 64);
        s2 += __shfl_xor(s2, off, 64);
        s3 += __shfl_xor(s3, off, 64);
    }
    if (lane == 0) {
        ctx_out[j]             = s0;
        ctx_out[C_DIM + j]     = s1;
        ctx_out[2 * C_DIM + j] = s2;
        ctx_out[3 * C_DIM + j] = s3;
    }
}

// ---------------------------------------------------------------------------
// Kernel 2 (R4): barrier-free LDS-free bf16x6 MFMA split-K GEMM.
// R4 changes: __launch_bounds__(256, 2) — R2/R3 showed VGPR_Count=80 while
// a fully-pipelined K-step needs ~136 live VGPRs; occupancy is GRID-limited
// (576 blocks ~ 9 waves/CU) so the 80-VGPR squeeze bought nothing and forced
// load serialization (MfmaUtil 11%, VALUBusy 10%, HBM 15%, all idle).
// Also: all 12 B-fragments hoisted into arrays before the 48 MFMAs.
// Blocks 512..575 compute cl[b][e].
// ---------------------------------------------------------------------------
__global__ __launch_bounds__(256, 2) void gemm_cl_kernel(
    const float* __restrict__ x, const ushort* __restrict__ gsp,
    const float* __restrict__ gw, const float* __restrict__ ctx,
    float* __restrict__ P, float* __restrict__ cl)
{
    if (blockIdx.x >= 128 * NSLICE) {
        const int lane = threadIdx.x & 63;
        const int pk   = (blockIdx.x - 128 * NSLICE) * 4 + (threadIdx.x >> 6); // 0..255
        const int b    = pk >> 6;
        const int e    = pk & 63;
        const float4* wr = (const float4*)(gw + (size_t)e * C_DIM);
        const float4* cr = (const float4*)(ctx + (size_t)b * C_DIM);
        float s = 0.f;
#pragma unroll
        for (int it = 0; it < 8; ++it) {
            float4 a = wr[it * 64 + lane];
            float4 c = cr[it * 64 + lane];
            s += a.x * c.x + a.y * c.y + a.z * c.z + a.w * c.w;
        }
#pragma unroll
        for (int off = 32; off; off >>= 1) s += __shfl_xor(s, off, 64);
        if (lane == 0) cl[pk] = s;
        return;
    }

    const int tid   = threadIdx.x;
    const int wv    = tid >> 6;
    const int lane  = tid & 63;
    const int l15   = lane & 15;
    const int quad  = lane >> 4;
    const int tile  = blockIdx.x & 127;     // 128 tiles x 128 tokens
    const int slice = blockIdx.x >> 7;      // 0..3
    const int tw    = tile * 128 + wv * 32; // wave token base
    const int cbase = slice * KSLICE;

    floatx4 acc[2][4];
#pragma unroll
    for (int s = 0; s < 2; ++s)
#pragma unroll
        for (int nt = 0; nt < 4; ++nt) acc[s][nt] = (floatx4){0.f, 0.f, 0.f, 0.f};

    const float* xr0 = x + (size_t)(tw + l15) * C_DIM + cbase + quad * 8;
    const float* xr1 = xr0 + (size_t)16 * C_DIM;
    const ushort* bb = gsp + ((size_t)((cbase >> 3) + quad) * 64 + l15) * 8;

    const int NKS = KSLICE / 32;            // 16 K=32 steps

    // prologue: issue ks=0 A-loads
    float4 a00 = *(const float4*)(xr0);
    float4 a01 = *(const float4*)(xr0 + 4);
    float4 a10 = *(const float4*)(xr1);
    float4 a11 = *(const float4*)(xr1 + 4);

#pragma unroll 2
    for (int ks = 0; ks < NKS; ++ks) {
        // --- issue next-iteration A-loads FIRST (T14: issue-early) ---
        const int nk = (ks + 1 < NKS) ? (ks + 1) : 0;
        float4 n00 = *(const float4*)(xr0 + nk * 32);
        float4 n01 = *(const float4*)(xr0 + nk * 32 + 4);
        float4 n10 = *(const float4*)(xr1 + nk * 32);
        float4 n11 = *(const float4*)(xr1 + nk * 32 + 4);

        // --- hoist all 12 B-fragments for this K-step (static indexing) ---
        const ushort* bks = bb + (size_t)ks * 4 * 64 * 8;  // 4 koct per step
        short8 bh[4], bm[4], bl[4];
#pragma unroll
        for (int nt = 0; nt < 4; ++nt) {
            const ushort* bp_ = bks + (size_t)(16 * nt) * 8;
            bh[nt] = *(const short8*)(bp_);
            bm[nt] = *(const short8*)(bp_ + GN);
            bl[nt] = *(const short8*)(bp_ + 2 * (size_t)GN);
        }

        // --- consume current A (loaded last iteration / prologue) ---
        short8 ah0, am0, al0, ah1, am1, al1;
        splitpack8(a00, a01, ah0, am0, al0);
        splitpack8(a10, a11, ah1, am1, al1);

#pragma unroll
        for (int nt = 0; nt < 4; ++nt) {
            acc[0][nt] = __builtin_amdgcn_mfma_f32_16x16x32_bf16(ah0, bh[nt], acc[0][nt], 0, 0, 0);
            acc[0][nt] = __builtin_amdgcn_mfma_f32_16x16x32_bf16(ah0, bm[nt], acc[0][nt], 0, 0, 0);
            acc[0][nt] = __builtin_amdgcn_mfma_f32_16x16x32_bf16(am0, bh[nt], acc[0][nt], 0, 0, 0);
            acc[0][nt] = __builtin_amdgcn_mfma_f32_16x16x32_bf16(ah0, bl[nt], acc[0][nt], 0, 0, 0);
            acc[0][nt] = __builtin_amdgcn_mfma_f32_16x16x32_bf16(al0, bh[nt], acc[0][nt], 0, 0, 0);
            acc[0][nt] = __builtin_amdgcn_mfma_f32_16x16x32_bf16(am0, bm[nt], acc[0][nt], 0, 0, 0);
            acc[1][nt] = __builtin_amdgcn_mfma_f32_16x16x32_bf16(ah1, bh[nt], acc[1][nt], 0, 0, 0);
            acc[1][nt] = __builtin_amdgcn_mfma_f32_16x16x32_bf16(ah1, bm[nt], acc[1][nt], 0, 0, 0);
            acc[1][nt] = __builtin_amdgcn_mfma_f32_16x16x32_bf16(am1, bh[nt], acc[1][nt], 0, 0, 0);
            acc[1][nt] = __builtin_amdgcn_mfma_f32_16x16x32_bf16(ah1, bl[nt], acc[1][nt], 0, 0, 0);
            acc[1][nt] = __builtin_amdgcn_mfma_f32_16x16x32_bf16(al1, bh[nt], acc[1][nt], 0, 0, 0);
            acc[1][nt] = __builtin_amdgcn_mfma_f32_16x16x32_bf16(am1, bm[nt], acc[1][nt], 0, 0, 0);
        }

        a00 = n00; a01 = n01; a10 = n10; a11 = n11;
    }

    // C/D layout (R6-verified): col=l15 (expert 16nt+l15), row=quad*4+r
    float* Ps = P + ((size_t)slice * T_TOKENS + tw) * E_EXP;
#pragma unroll
    for (int s = 0; s < 2; ++s)
#pragma unroll
        for (int nt = 0; nt < 4; ++nt)
#pragma unroll
            for (int r = 0; r < 4; ++r)
                Ps[(size_t)(s * 16 + quad * 4 + r) * E_EXP + 16 * nt + l15] =
                    acc[s][nt][r];
}

// ---------------------------------------------------------------------------
// Kernel 3 (epilogue, proven): deterministic slice sum + cl[b][e], fused
// top-2+sumexp butterfly, per-block LDS reduce -> bp[block][128].
// ---------------------------------------------------------------------------
__global__ __launch_bounds__(256) void epilogue_kernel(
    const float* __restrict__ P, const float* __restrict__ cl,
    float* __restrict__ out, float* __restrict__ bp)
{
    __shared__ float red[4][128];

    const int tid  = threadIdx.x;
    const int wv   = tid >> 6;
    const int lane = tid & 63;
    const int t0   = blockIdx.x * (T_TOKENS / EPB);     // 16 tokens
    const float clv = cl[(t0 >> 12) * 64 + lane];       // batch = t0/4096

    float imp_acc = 0.f, cnt_acc = 0.f;

    for (int tt = 0; tt < 4; ++tt) {
        const int t = t0 + wv * 4 + tt;
        float v = clv;
#pragma unroll
        for (int s = 0; s < NSLICE; ++s)
            v += P[((size_t)s * T_TOKENS + t) * E_EXP + lane];

        const float p = expf(v);
        float v1 = v;  int i1 = lane;
        float v2 = -INFINITY; int i2 = 0x7fffffff;
        float s = p;
#pragma unroll
        for (int off = 32; off; off >>= 1) {
            float ov1 = __shfl_xor(v1, off, 64);
            int   oi1 = __shfl_xor(i1, off, 64);
            float ov2 = __shfl_xor(v2, off, 64);
            int   oi2 = __shfl_xor(i2, off, 64);
            s += __shfl_xor(s, off, 64);
            const bool aw = (ov1 < v1) || (ov1 == v1 && i1 < oi1);
            const float lv = aw ? ov1 : v1;  const int li = aw ? oi1 : i1;
            const float wv2 = aw ? v2 : ov2; const int wi = aw ? i2 : oi2;
            if (!aw) { v1 = ov1; i1 = oi1; }
            const bool sw = (wv2 < lv) || (wv2 == lv && li < wi);
            v2 = sw ? lv : wv2; i2 = sw ? li : wi;
        }

        imp_acc += p / s;
        if (lane == i1 || lane == i2) cnt_acc += 1.f;

        if (lane == 0) {
            const float e2 = expf(v2 - v1);
            out[2 * t]     = (float)i1;
            out[2 * t + 1] = (float)i2;
            out[2 * T_TOKENS + 2 * t]     = 1.f / (1.f + e2);
            out[2 * T_TOKENS + 2 * t + 1] = e2 / (1.f + e2);
        }
    }

    red[wv][lane]      = imp_acc;
    red[wv][64 + lane] = cnt_acc;
    __syncthreads();
    if (tid < 128) {
        float s = red[0][tid] + red[1][tid] + red[2][tid] + red[3][tid];
        bp[(size_t)blockIdx.x * 128 + tid] = s;
    }
}

// ---------------------------------------------------------------------------
// Kernel 4: parallel bp reduce -> aux loss (proven R5)
// ---------------------------------------------------------------------------
__global__ __launch_bounds__(1024) void aux_kernel(
    const float* __restrict__ bp, int nb, float* __restrict__ out_aux)
{
    __shared__ float4 red[32][32];
    const int tid = threadIdx.x;
    const int c4  = tid & 31;
    const int grp = tid >> 5;

    const float4* bp4 = (const float4*)bp;
    float4 s = make_float4(0.f, 0.f, 0.f, 0.f);
    for (int r = grp; r < nb; r += 32) {
        float4 v = bp4[(size_t)r * 32 + c4];
        s.x += v.x; s.y += v.y; s.z += v.z; s.w += v.w;
    }
    red[grp][c4] = s;
    __syncthreads();

    if (tid < 32) {
        float4 t = make_float4(0.f, 0.f, 0.f, 0.f);
#pragma unroll
        for (int g = 0; g < 32; ++g) {
            float4 v = red[g][tid];
            t.x += v.x; t.y += v.y; t.z += v.z; t.w += v.w;
        }
        red[0][tid] = t;
    }
    __syncthreads();

    if (tid < 16) {
        float4 a = red[0][tid];
        float4 b = red[0][tid + 16];
        float v = a.x * b.x + a.y * b.y + a.z * b.z + a.w * b.w;
#pragma unroll
        for (int off = 8; off; off >>= 1) v += __shfl_xor(v, off, 64);
        if (tid == 0)
            out_aux[0] = (float)E_EXP * v / ((float)T_TOKENS * (float)T_TOKENS);
    }
}

// ---------------------------------------------------------------------------
// Fallback fused fp32 kernel (proven R5) — used only if ws too small
// ---------------------------------------------------------------------------
#define TM    64
#define FKC   64
#define FLSTR 68
__global__ __launch_bounds__(256) void router_fused_kernel(
    const float* __restrict__ x, const float* __restrict__ gate_w,
    const float* __restrict__ ctx, float* __restrict__ out,
    float* __restrict__ bp)
{
    __shared__ float xs[TM][FLSTR];
    __shared__ float gs[E_EXP][FLSTR];
    __shared__ float ls[TM][FLSTR];
    __shared__ float red[4][128];

    const int tid = threadIdx.x;
    const int eg  = tid & 15;
    const int tg  = tid >> 4;
    const int t0  = blockIdx.x * TM;
    const int b   = t0 / N_SEQ;
    const int sr  = tid >> 4;
    const int scg = tid & 15;
    const float* ctx_row = ctx + (size_t)b * C_DIM;

    float4 acc[4][4];
#pragma unroll
    for (int i = 0; i < 4; ++i)
#pragma unroll
        for (int j = 0; j < 4; ++j) acc[i][j] = make_float4(0.f, 0.f, 0.f, 0.f);

    float4 px[4], pg[4], pc;
    auto prefetch = [&](int kc) {
        const int c0 = kc * FKC + scg * 4;
        pc = *(const float4*)(ctx_row + c0);
#pragma unroll
        for (int i = 0; i < 4; ++i) {
            px[i] = *(const float4*)(x + (size_t)(t0 + sr + 16 * i) * C_DIM + c0);
            pg[i] = *(const float4*)(gate_w + (size_t)(sr + 16 * i) * C_DIM + c0);
        }
    };

    prefetch(0);
    const int NCHUNK = C_DIM / FKC;
    for (int kc = 0; kc < NCHUNK; ++kc) {
        __syncthreads();
#pragma unroll
        for (int i = 0; i < 4; ++i) {
            float4 v = px[i];
            v.x += pc.x; v.y += pc.y; v.z += pc.z; v.w += pc.w;
            *(float4*)&xs[sr + 16 * i][scg * 4] = v;
            *(float4*)&gs[sr + 16 * i][scg * 4] = pg[i];
        }
        __syncthreads();
        if (kc + 1 < NCHUNK) prefetch(kc + 1);
#pragma unroll
        for (int cc = 0; cc < FKC; cc += 4) {
            float4 xv[4], gv[4];
#pragma unroll
            for (int i = 0; i < 4; ++i) xv[i] = *(const float4*)&xs[tg + 16 * i][cc];
#pragma unroll
            for (int j = 0; j < 4; ++j) gv[j] = *(const float4*)&gs[eg + 16 * j][cc];
#pragma unroll
            for (int i = 0; i < 4; ++i)
#pragma unroll
                for (int j = 0; j < 4; ++j) {
                    acc[i][j].x = fmaf(xv[i].x, gv[j].x, acc[i][j].x);
                    acc[i][j].y = fmaf(xv[i].y, gv[j].y, acc[i][j].y);
                    acc[i][j].z = fmaf(xv[i].z, gv[j].z, acc[i][j].z);
                    acc[i][j].w = fmaf(xv[i].w, gv[j].w, acc[i][j].w);
                }
        }
    }

    __syncthreads();
#pragma unroll
    for (int i = 0; i < 4; ++i)
#pragma unroll
        for (int j = 0; j < 4; ++j)
            ls[tg + 16 * i][eg + 16 * j] =
                (acc[i][j].x + acc[i][j].y) + (acc[i][j].z + acc[i][j].w);
    __syncthreads();

    const int wv   = tid >> 6;
    const int lane = tid & 63;
    float imp_acc = 0.f, cnt_acc = 0.f;

    for (int tt = 0; tt < 16; ++tt) {
        const int tokL = wv * 16 + tt;
        const float v = ls[tokL][lane];
        const float p = expf(v);
        float v1 = v;  int i1 = lane;
        float v2 = -INFINITY; int i2 = 0x7fffffff;
        float s = p;
#pragma unroll
        for (int off = 32; off; off >>= 1) {
            float ov1 = __shfl_xor(v1, off, 64);
            int   oi1 = __shfl_xor(i1, off, 64);
            float ov2 = __shfl_xor(v2, off, 64);
            int   oi2 = __shfl_xor(i2, off, 64);
            s += __shfl_xor(s, off, 64);
            const bool aw = (ov1 < v1) || (ov1 == v1 && i1 < oi1);
            const float lv = aw ? ov1 : v1;  const int li = aw ? oi1 : i1;
            const float wv2 = aw ? v2 : ov2; const int wi = aw ? i2 : oi2;
            if (!aw) { v1 = ov1; i1 = oi1; }
            const bool sw = (wv2 < lv) || (wv2 == lv && li < wi);
            v2 = sw ? lv : wv2; i2 = sw ? li : wi;
        }
        imp_acc += p / s;
        if (lane == i1 || lane == i2) cnt_acc += 1.f;
        if (lane == 0) {
            const int t = t0 + tokL;
            const float e2 = expf(v2 - v1);
            out[2 * t]     = (float)i1;
            out[2 * t + 1] = (float)i2;
            out[2 * T_TOKENS + 2 * t]     = 1.f / (1.f + e2);
            out[2 * T_TOKENS + 2 * t + 1] = e2 / (1.f + e2);
        }
    }

    red[wv][lane]      = imp_acc;
    red[wv][64 + lane] = cnt_acc;
    __syncthreads();
    if (tid < 128) {
        float s = red[0][tid] + red[1][tid] + red[2][tid] + red[3][tid];
        bp[(size_t)blockIdx.x * 128 + tid] = s;
    }
}

extern "C" void kernel_launch(void* const* d_in, const int* in_sizes, int n_in,
                              void* d_out, int out_size, void* d_ws, size_t ws_size,
                              hipStream_t stream)
{
    (void)in_sizes; (void)n_in; (void)out_size;
    const float* x      = (const float*)d_in[0];
    const float* rc     = (const float*)d_in[1];
    const float* gate_w = (const float*)d_in[2];
    const float* ctx_w  = (const float*)d_in[3];
    float* out = (float*)d_out;

    float*  ctx = (float*)d_ws;                            // 8192 f
    float*  cl  = ctx + 8192;                              // 256 f
    float*  bp  = cl + 256;                                // EPB*128 f
    float*  P   = bp + (size_t)EPB * 128;                  // NSLICE*T*E f
    ushort* gsp = (ushort*)(P + (size_t)NSLICE * T_TOKENS * E_EXP); // 3*GN us

    const size_t need =
        (8192 + 256 + (size_t)EPB * 128 + (size_t)NSLICE * T_TOKENS * E_EXP)
            * sizeof(float)
        + (size_t)3 * GN * sizeof(ushort);

    if (ws_size >= need) {
        pre_kernel<<<512, 256, 0, stream>>>(rc, ctx_w, gate_w, ctx, gsp);
        gemm_cl_kernel<<<128 * NSLICE + 64, 256, 0, stream>>>(x, gsp, gate_w, ctx, P, cl);
        epilogue_kernel<<<EPB, 256, 0, stream>>>(P, cl, out, bp);
        aux_kernel<<<1, 1024, 0, stream>>>(bp, EPB, out + 2 * 2 * T_TOKENS);
    } else {
        pre_kernel<<<512, 256, 0, stream>>>(rc, ctx_w, gate_w, ctx, nullptr);
        router_fused_kernel<<<256, 256, 0, stream>>>(x, gate_w, ctx, out, bp);
        aux_kernel<<<1, 1024, 0, stream>>>(bp, 256, out + 2 * 2 * T_TOKENS);
    }
}

// Round 5
// 245.815 us; speedup vs baseline: 1.3650x; 1.0014x over previous
//
#include <hip/hip_runtime.h>
#include <math.h>

// Problem constants: B=4, N=4096, C=2048, E=64, K=2
#define T_TOKENS 16384
#define C_DIM    2048
#define N_SEQ    4096
#define E_EXP    64
#define NSLICE   4        // split-K slices (R2: 8 regressed; 4 proven)
#define KSLICE   512      // C_DIM / NSLICE
#define EPB      1024     // epilogue blocks
#define GN       131072   // gate elements per split part (64*2048)

typedef __attribute__((ext_vector_type(8))) short  short8;   // 8 bf16 = 4 VGPR
typedef __attribute__((ext_vector_type(4))) float  floatx4;

// ---- exact 3-way bf16 decomposition (truncation; residuals exact) ----------
__device__ __forceinline__ void splitv(float v, ushort& h, ushort& m, ushort& l) {
    unsigned u = __float_as_uint(v);
    h = (ushort)(u >> 16);
    float f1 = v - __uint_as_float(u & 0xffff0000u);       // exact
    unsigned u1 = __float_as_uint(f1);
    m = (ushort)(u1 >> 16);
    float f2 = f1 - __uint_as_float(u1 & 0xffff0000u);     // exact
    l = (ushort)(__float_as_uint(f2) >> 16);
}

__device__ __forceinline__ void splitpack8(const float4& a, const float4& b,
                                           short8& h, short8& m, short8& l) {
    ushort hh, mm, ll;
    splitv(a.x, hh, mm, ll); h[0] = hh; m[0] = mm; l[0] = ll;
    splitv(a.y, hh, mm, ll); h[1] = hh; m[1] = mm; l[1] = ll;
    splitv(a.z, hh, mm, ll); h[2] = hh; m[2] = mm; l[2] = ll;
    splitv(a.w, hh, mm, ll); h[3] = hh; m[3] = mm; l[3] = ll;
    splitv(b.x, hh, mm, ll); h[4] = hh; m[4] = mm; l[4] = ll;
    splitv(b.y, hh, mm, ll); h[5] = hh; m[5] = mm; l[5] = ll;
    splitv(b.z, hh, mm, ll); h[6] = hh; m[6] = mm; l[6] = ll;
    splitv(b.w, hh, mm, ll); h[7] = hh; m[7] = mm; l[7] = ll;
}

// RNE split for the one-time gate_w preprocessing
__device__ __forceinline__ void split3rne(float v, ushort& h, ushort& m, ushort& l) {
    unsigned u = __float_as_uint(v);
    unsigned r = (u + 0x7fffu + ((u >> 16) & 1u)) >> 16;
    h = (ushort)r;
    float e1 = v - __uint_as_float(r << 16);
    u = __float_as_uint(e1);
    r = (u + 0x7fffu + ((u >> 16) & 1u)) >> 16;
    m = (ushort)r;
    float e2 = e1 - __uint_as_float(r << 16);
    l = (ushort)(__float_as_uint(e2) >> 16);
}

// ---- shared ctx body: wave computes ctx[0..3][j] (bit-identical to R0) ----
__device__ __forceinline__ void ctx_body(
    int j, int lane, const float* __restrict__ rc,
    const float* __restrict__ ctx_w, float* __restrict__ ctx_out)
{
    const float4* wr = (const float4*)(ctx_w + (size_t)j * C_DIM);
    const float4* r0 = (const float4*)(rc);
    const float4* r1 = (const float4*)(rc + C_DIM);
    const float4* r2 = (const float4*)(rc + 2 * C_DIM);
    const float4* r3 = (const float4*)(rc + 3 * C_DIM);

    float s0 = 0.f, s1 = 0.f, s2 = 0.f, s3 = 0.f;
#pragma unroll
    for (int it = 0; it < 8; ++it) {
        float4 a  = wr[it * 64 + lane];
        float4 c0 = r0[it * 64 + lane];
        float4 c1 = r1[it * 64 + lane];
        float4 c2 = r2[it * 64 + lane];
        float4 c3 = r3[it * 64 + lane];
        s0 += a.x * c0.x + a.y * c0.y + a.z * c0.z + a.w * c0.w;
        s1 += a.x * c1.x + a.y * c1.y + a.z * c1.z + a.w * c1.w;
        s2 += a.x * c2.x + a.y * c2.y + a.z * c2.z + a.w * c2.w;
        s3 += a.x * c3.x + a.y * c3.y + a.z * c3.z + a.w * c3.w;
    }
#pragma unroll
    for (int off = 32; off; off >>= 1) {
        s0 += __shfl_xor(s0, off, 64);
        s1 += __shfl_xor(s1, off, 64);
        s2 += __shfl_xor(s2, off, 64);
        s3 += __shfl_xor(s3, off, 64);
    }
    if (lane == 0) {
        ctx_out[j]             = s0;
        ctx_out[C_DIM + j]     = s1;
        ctx_out[2 * C_DIM + j] = s2;
        ctx_out[3 * C_DIM + j] = s3;
    }
}

// ---------------------------------------------------------------------------
// Kernel 1 (R5): gsp split ONLY — tiny (0.5 MB read / 0.75 MB write), runs
// first into the dirty-L3 poison storm with bounded cost. The big readers
// come AFTER so they overlap the L3->HBM poison writeback drain.
// ---------------------------------------------------------------------------
__global__ __launch_bounds__(256) void split_kernel(
    const float* __restrict__ gw, ushort* __restrict__ gsp)
{
    const int idx  = blockIdx.x * 256 + threadIdx.x;   // 0..131071
    const int j    = idx & 7;
    const int e    = (idx >> 3) & 63;
    const int koct = idx >> 9;
    float g = gw[(size_t)e * C_DIM + koct * 8 + j];
    ushort h, m, l;
    split3rne(g, h, m, l);
    gsp[idx]          = h;
    gsp[GN + idx]     = m;
    gsp[2 * GN + idx] = l;
}

// ---------------------------------------------------------------------------
// Kernel 2 (R5): blocks 0..511 = the R4 gemm body (barrier-free LDS-free
// bf16x6 MFMA split-K, next-A prefetch, B-hoist, launch_bounds(256,2));
// blocks 512..1023 = ctx (independent of gemm; 16.8 MB ctx_w read overlaps
// the gemm's HBM stream + poison writeback). Runs SECOND so this biggest
// HBM reader absorbs the L3 poison drain — and becomes top-5 visible.
// ---------------------------------------------------------------------------
__global__ __launch_bounds__(256, 2) void gemm_ctx_kernel(
    const float* __restrict__ x, const ushort* __restrict__ gsp,
    const float* __restrict__ rc, const float* __restrict__ ctx_w,
    float* __restrict__ ctx_out, float* __restrict__ P)
{
    if (blockIdx.x >= 128 * NSLICE) {
        const int lane = threadIdx.x & 63;
        const int j = (blockIdx.x - 128 * NSLICE) * 4 + (threadIdx.x >> 6); // 0..2047
        ctx_body(j, lane, rc, ctx_w, ctx_out);
        return;
    }

    const int tid   = threadIdx.x;
    const int wv    = tid >> 6;
    const int lane  = tid & 63;
    const int l15   = lane & 15;
    const int quad  = lane >> 4;
    const int tile  = blockIdx.x & 127;     // 128 tiles x 128 tokens
    const int slice = blockIdx.x >> 7;      // 0..3
    const int tw    = tile * 128 + wv * 32; // wave token base
    const int cbase = slice * KSLICE;

    floatx4 acc[2][4];
#pragma unroll
    for (int s = 0; s < 2; ++s)
#pragma unroll
        for (int nt = 0; nt < 4; ++nt) acc[s][nt] = (floatx4){0.f, 0.f, 0.f, 0.f};

    const float* xr0 = x + (size_t)(tw + l15) * C_DIM + cbase + quad * 8;
    const float* xr1 = xr0 + (size_t)16 * C_DIM;
    const ushort* bb = gsp + ((size_t)((cbase >> 3) + quad) * 64 + l15) * 8;

    const int NKS = KSLICE / 32;            // 16 K=32 steps

    // prologue: issue ks=0 A-loads
    float4 a00 = *(const float4*)(xr0);
    float4 a01 = *(const float4*)(xr0 + 4);
    float4 a10 = *(const float4*)(xr1);
    float4 a11 = *(const float4*)(xr1 + 4);

#pragma unroll 2
    for (int ks = 0; ks < NKS; ++ks) {
        // --- issue next-iteration A-loads FIRST (T14: issue-early) ---
        const int nk = (ks + 1 < NKS) ? (ks + 1) : 0;
        float4 n00 = *(const float4*)(xr0 + nk * 32);
        float4 n01 = *(const float4*)(xr0 + nk * 32 + 4);
        float4 n10 = *(const float4*)(xr1 + nk * 32);
        float4 n11 = *(const float4*)(xr1 + nk * 32 + 4);

        // --- hoist all 12 B-fragments for this K-step (static indexing) ---
        const ushort* bks = bb + (size_t)ks * 4 * 64 * 8;  // 4 koct per step
        short8 bh[4], bm[4], bl[4];
#pragma unroll
        for (int nt = 0; nt < 4; ++nt) {
            const ushort* bp_ = bks + (size_t)(16 * nt) * 8;
            bh[nt] = *(const short8*)(bp_);
            bm[nt] = *(const short8*)(bp_ + GN);
            bl[nt] = *(const short8*)(bp_ + 2 * (size_t)GN);
        }

        // --- consume current A (loaded last iteration / prologue) ---
        short8 ah0, am0, al0, ah1, am1, al1;
        splitpack8(a00, a01, ah0, am0, al0);
        splitpack8(a10, a11, ah1, am1, al1);

#pragma unroll
        for (int nt = 0; nt < 4; ++nt) {
            acc[0][nt] = __builtin_amdgcn_mfma_f32_16x16x32_bf16(ah0, bh[nt], acc[0][nt], 0, 0, 0);
            acc[0][nt] = __builtin_amdgcn_mfma_f32_16x16x32_bf16(ah0, bm[nt], acc[0][nt], 0, 0, 0);
            acc[0][nt] = __builtin_amdgcn_mfma_f32_16x16x32_bf16(am0, bh[nt], acc[0][nt], 0, 0, 0);
            acc[0][nt] = __builtin_amdgcn_mfma_f32_16x16x32_bf16(ah0, bl[nt], acc[0][nt], 0, 0, 0);
            acc[0][nt] = __builtin_amdgcn_mfma_f32_16x16x32_bf16(al0, bh[nt], acc[0][nt], 0, 0, 0);
            acc[0][nt] = __builtin_amdgcn_mfma_f32_16x16x32_bf16(am0, bm[nt], acc[0][nt], 0, 0, 0);
            acc[1][nt] = __builtin_amdgcn_mfma_f32_16x16x32_bf16(ah1, bh[nt], acc[1][nt], 0, 0, 0);
            acc[1][nt] = __builtin_amdgcn_mfma_f32_16x16x32_bf16(ah1, bm[nt], acc[1][nt], 0, 0, 0);
            acc[1][nt] = __builtin_amdgcn_mfma_f32_16x16x32_bf16(am1, bh[nt], acc[1][nt], 0, 0, 0);
            acc[1][nt] = __builtin_amdgcn_mfma_f32_16x16x32_bf16(ah1, bl[nt], acc[1][nt], 0, 0, 0);
            acc[1][nt] = __builtin_amdgcn_mfma_f32_16x16x32_bf16(al1, bh[nt], acc[1][nt], 0, 0, 0);
            acc[1][nt] = __builtin_amdgcn_mfma_f32_16x16x32_bf16(am1, bm[nt], acc[1][nt], 0, 0, 0);
        }

        a00 = n00; a01 = n01; a10 = n10; a11 = n11;
    }

    // C/D layout (R6-verified): col=l15 (expert 16nt+l15), row=quad*4+r
    float* Ps = P + ((size_t)slice * T_TOKENS + tw) * E_EXP;
#pragma unroll
    for (int s = 0; s < 2; ++s)
#pragma unroll
        for (int nt = 0; nt < 4; ++nt)
#pragma unroll
            for (int r = 0; r < 4; ++r)
                Ps[(size_t)(s * 16 + quad * 4 + r) * E_EXP + 16 * nt + l15] =
                    acc[s][nt][r];
}

// ---------------------------------------------------------------------------
// Kernel 3 (R5): cl[b][e] = dot(ctx[b,:], gate_w[e,:]) — 64 blocks, tiny.
// Runs after gemm_ctx (needs ctx). Bit-identical math to prior cl path.
// ---------------------------------------------------------------------------
__global__ __launch_bounds__(256) void cl_kernel(
    const float* __restrict__ gw, const float* __restrict__ ctx,
    float* __restrict__ cl)
{
    const int lane = threadIdx.x & 63;
    const int pk   = blockIdx.x * 4 + (threadIdx.x >> 6);  // 0..255
    const int b    = pk >> 6;
    const int e    = pk & 63;
    const float4* wr = (const float4*)(gw + (size_t)e * C_DIM);
    const float4* cr = (const float4*)(ctx + (size_t)b * C_DIM);
    float s = 0.f;
#pragma unroll
    for (int it = 0; it < 8; ++it) {
        float4 a = wr[it * 64 + lane];
        float4 c = cr[it * 64 + lane];
        s += a.x * c.x + a.y * c.y + a.z * c.z + a.w * c.w;
    }
#pragma unroll
    for (int off = 32; off; off >>= 1) s += __shfl_xor(s, off, 64);
    if (lane == 0) cl[pk] = s;
}

// ---------------------------------------------------------------------------
// Kernel 4 (epilogue, proven): deterministic slice sum + cl[b][e], fused
// top-2+sumexp butterfly, per-block LDS reduce -> bp[block][128].
// ---------------------------------------------------------------------------
__global__ __launch_bounds__(256) void epilogue_kernel(
    const float* __restrict__ P, const float* __restrict__ cl,
    float* __restrict__ out, float* __restrict__ bp)
{
    __shared__ float red[4][128];

    const int tid  = threadIdx.x;
    const int wv   = tid >> 6;
    const int lane = tid & 63;
    const int t0   = blockIdx.x * (T_TOKENS / EPB);     // 16 tokens
    const float clv = cl[(t0 >> 12) * 64 + lane];       // batch = t0/4096

    float imp_acc = 0.f, cnt_acc = 0.f;

    for (int tt = 0; tt < 4; ++tt) {
        const int t = t0 + wv * 4 + tt;
        float v = clv;
#pragma unroll
        for (int s = 0; s < NSLICE; ++s)
            v += P[((size_t)s * T_TOKENS + t) * E_EXP + lane];

        const float p = expf(v);
        float v1 = v;  int i1 = lane;
        float v2 = -INFINITY; int i2 = 0x7fffffff;
        float s = p;
#pragma unroll
        for (int off = 32; off; off >>= 1) {
            float ov1 = __shfl_xor(v1, off, 64);
            int   oi1 = __shfl_xor(i1, off, 64);
            float ov2 = __shfl_xor(v2, off, 64);
            int   oi2 = __shfl_xor(i2, off, 64);
            s += __shfl_xor(s, off, 64);
            const bool aw = (ov1 < v1) || (ov1 == v1 && i1 < oi1);
            const float lv = aw ? ov1 : v1;  const int li = aw ? oi1 : i1;
            const float wv2 = aw ? v2 : ov2; const int wi = aw ? i2 : oi2;
            if (!aw) { v1 = ov1; i1 = oi1; }
            const bool sw = (wv2 < lv) || (wv2 == lv && li < wi);
            v2 = sw ? lv : wv2; i2 = sw ? li : wi;
        }

        imp_acc += p / s;
        if (lane == i1 || lane == i2) cnt_acc += 1.f;

        if (lane == 0) {
            const float e2 = expf(v2 - v1);
            out[2 * t]     = (float)i1;
            out[2 * t + 1] = (float)i2;
            out[2 * T_TOKENS + 2 * t]     = 1.f / (1.f + e2);
            out[2 * T_TOKENS + 2 * t + 1] = e2 / (1.f + e2);
        }
    }

    red[wv][lane]      = imp_acc;
    red[wv][64 + lane] = cnt_acc;
    __syncthreads();
    if (tid < 128) {
        float s = red[0][tid] + red[1][tid] + red[2][tid] + red[3][tid];
        bp[(size_t)blockIdx.x * 128 + tid] = s;
    }
}

// ---------------------------------------------------------------------------
// Kernel 5: parallel bp reduce -> aux loss (proven R5)
// ---------------------------------------------------------------------------
__global__ __launch_bounds__(1024) void aux_kernel(
    const float* __restrict__ bp, int nb, float* __restrict__ out_aux)
{
    __shared__ float4 red[32][32];
    const int tid = threadIdx.x;
    const int c4  = tid & 31;
    const int grp = tid >> 5;

    const float4* bp4 = (const float4*)bp;
    float4 s = make_float4(0.f, 0.f, 0.f, 0.f);
    for (int r = grp; r < nb; r += 32) {
        float4 v = bp4[(size_t)r * 32 + c4];
        s.x += v.x; s.y += v.y; s.z += v.z; s.w += v.w;
    }
    red[grp][c4] = s;
    __syncthreads();

    if (tid < 32) {
        float4 t = make_float4(0.f, 0.f, 0.f, 0.f);
#pragma unroll
        for (int g = 0; g < 32; ++g) {
            float4 v = red[g][tid];
            t.x += v.x; t.y += v.y; t.z += v.z; t.w += v.w;
        }
        red[0][tid] = t;
    }
    __syncthreads();

    if (tid < 16) {
        float4 a = red[0][tid];
        float4 b = red[0][tid + 16];
        float v = a.x * b.x + a.y * b.y + a.z * b.z + a.w * b.w;
#pragma unroll
        for (int off = 8; off; off >>= 1) v += __shfl_xor(v, off, 64);
        if (tid == 0)
            out_aux[0] = (float)E_EXP * v / ((float)T_TOKENS * (float)T_TOKENS);
    }
}

// ---------------------------------------------------------------------------
// Fallback path kernels (ws too small): ctx-only + fused fp32 + aux
// ---------------------------------------------------------------------------
__global__ __launch_bounds__(256) void ctx_only_kernel(
    const float* __restrict__ rc, const float* __restrict__ ctx_w,
    float* __restrict__ ctx_out)
{
    const int lane = threadIdx.x & 63;
    const int j    = blockIdx.x * 4 + (threadIdx.x >> 6);
    ctx_body(j, lane, rc, ctx_w, ctx_out);
}

#define TM    64
#define FKC   64
#define FLSTR 68
__global__ __launch_bounds__(256) void router_fused_kernel(
    const float* __restrict__ x, const float* __restrict__ gate_w,
    const float* __restrict__ ctx, float* __restrict__ out,
    float* __restrict__ bp)
{
    __shared__ float xs[TM][FLSTR];
    __shared__ float gs[E_EXP][FLSTR];
    __shared__ float ls[TM][FLSTR];
    __shared__ float red[4][128];

    const int tid = threadIdx.x;
    const int eg  = tid & 15;
    const int tg  = tid >> 4;
    const int t0  = blockIdx.x * TM;
    const int b   = t0 / N_SEQ;
    const int sr  = tid >> 4;
    const int scg = tid & 15;
    const float* ctx_row = ctx + (size_t)b * C_DIM;

    float4 acc[4][4];
#pragma unroll
    for (int i = 0; i < 4; ++i)
#pragma unroll
        for (int j = 0; j < 4; ++j) acc[i][j] = make_float4(0.f, 0.f, 0.f, 0.f);

    float4 px[4], pg[4], pc;
    auto prefetch = [&](int kc) {
        const int c0 = kc * FKC + scg * 4;
        pc = *(const float4*)(ctx_row + c0);
#pragma unroll
        for (int i = 0; i < 4; ++i) {
            px[i] = *(const float4*)(x + (size_t)(t0 + sr + 16 * i) * C_DIM + c0);
            pg[i] = *(const float4*)(gate_w + (size_t)(sr + 16 * i) * C_DIM + c0);
        }
    };

    prefetch(0);
    const int NCHUNK = C_DIM / FKC;
    for (int kc = 0; kc < NCHUNK; ++kc) {
        __syncthreads();
#pragma unroll
        for (int i = 0; i < 4; ++i) {
            float4 v = px[i];
            v.x += pc.x; v.y += pc.y; v.z += pc.z; v.w += pc.w;
            *(float4*)&xs[sr + 16 * i][scg * 4] = v;
            *(float4*)&gs[sr + 16 * i][scg * 4] = pg[i];
        }
        __syncthreads();
        if (kc + 1 < NCHUNK) prefetch(kc + 1);
#pragma unroll
        for (int cc = 0; cc < FKC; cc += 4) {
            float4 xv[4], gv[4];
#pragma unroll
            for (int i = 0; i < 4; ++i) xv[i] = *(const float4*)&xs[tg + 16 * i][cc];
#pragma unroll
            for (int j = 0; j < 4; ++j) gv[j] = *(const float4*)&gs[eg + 16 * j][cc];
#pragma unroll
            for (int i = 0; i < 4; ++i)
#pragma unroll
                for (int j = 0; j < 4; ++j) {
                    acc[i][j].x = fmaf(xv[i].x, gv[j].x, acc[i][j].x);
                    acc[i][j].y = fmaf(xv[i].y, gv[j].y, acc[i][j].y);
                    acc[i][j].z = fmaf(xv[i].z, gv[j].z, acc[i][j].z);
                    acc[i][j].w = fmaf(xv[i].w, gv[j].w, acc[i][j].w);
                }
        }
    }

    __syncthreads();
#pragma unroll
    for (int i = 0; i < 4; ++i)
#pragma unroll
        for (int j = 0; j < 4; ++j)
            ls[tg + 16 * i][eg + 16 * j] =
                (acc[i][j].x + acc[i][j].y) + (acc[i][j].z + acc[i][j].w);
    __syncthreads();

    const int wv   = tid >> 6;
    const int lane = tid & 63;
    float imp_acc = 0.f, cnt_acc = 0.f;

    for (int tt = 0; tt < 16; ++tt) {
        const int tokL = wv * 16 + tt;
        const float v = ls[tokL][lane];
        const float p = expf(v);
        float v1 = v;  int i1 = lane;
        float v2 = -INFINITY; int i2 = 0x7fffffff;
        float s = p;
#pragma unroll
        for (int off = 32; off; off >>= 1) {
            float ov1 = __shfl_xor(v1, off, 64);
            int   oi1 = __shfl_xor(i1, off, 64);
            float ov2 = __shfl_xor(v2, off, 64);
            int   oi2 = __shfl_xor(i2, off, 64);
            s += __shfl_xor(s, off, 64);
            const bool aw = (ov1 < v1) || (ov1 == v1 && i1 < oi1);
            const float lv = aw ? ov1 : v1;  const int li = aw ? oi1 : i1;
            const float wv2 = aw ? v2 : ov2; const int wi = aw ? i2 : oi2;
            if (!aw) { v1 = ov1; i1 = oi1; }
            const bool sw = (wv2 < lv) || (wv2 == lv && li < wi);
            v2 = sw ? lv : wv2; i2 = sw ? li : wi;
        }
        imp_acc += p / s;
        if (lane == i1 || lane == i2) cnt_acc += 1.f;
        if (lane == 0) {
            const int t = t0 + tokL;
            const float e2 = expf(v2 - v1);
            out[2 * t]     = (float)i1;
            out[2 * t + 1] = (float)i2;
            out[2 * T_TOKENS + 2 * t]     = 1.f / (1.f + e2);
            out[2 * T_TOKENS + 2 * t + 1] = e2 / (1.f + e2);
        }
    }

    red[wv][lane]      = imp_acc;
    red[wv][64 + lane] = cnt_acc;
    __syncthreads();
    if (tid < 128) {
        float s = red[0][tid] + red[1][tid] + red[2][tid] + red[3][tid];
        bp[(size_t)blockIdx.x * 128 + tid] = s;
    }
}

extern "C" void kernel_launch(void* const* d_in, const int* in_sizes, int n_in,
                              void* d_out, int out_size, void* d_ws, size_t ws_size,
                              hipStream_t stream)
{
    (void)in_sizes; (void)n_in; (void)out_size;
    const float* x      = (const float*)d_in[0];
    const float* rc     = (const float*)d_in[1];
    const float* gate_w = (const float*)d_in[2];
    const float* ctx_w  = (const float*)d_in[3];
    float* out = (float*)d_out;

    float*  ctx = (float*)d_ws;                            // 8192 f
    float*  cl  = ctx + 8192;                              // 256 f
    float*  bp  = cl + 256;                                // EPB*128 f
    float*  P   = bp + (size_t)EPB * 128;                  // NSLICE*T*E f
    ushort* gsp = (ushort*)(P + (size_t)NSLICE * T_TOKENS * E_EXP); // 3*GN us

    const size_t need =
        (8192 + 256 + (size_t)EPB * 128 + (size_t)NSLICE * T_TOKENS * E_EXP)
            * sizeof(float)
        + (size_t)3 * GN * sizeof(ushort);

    if (ws_size >= need) {
        split_kernel<<<512, 256, 0, stream>>>(gate_w, gsp);
        gemm_ctx_kernel<<<128 * NSLICE + 512, 256, 0, stream>>>(
            x, gsp, rc, ctx_w, ctx, P);
        cl_kernel<<<64, 256, 0, stream>>>(gate_w, ctx, cl);
        epilogue_kernel<<<EPB, 256, 0, stream>>>(P, cl, out, bp);
        aux_kernel<<<1, 1024, 0, stream>>>(bp, EPB, out + 2 * 2 * T_TOKENS);
    } else {
        ctx_only_kernel<<<512, 256, 0, stream>>>(rc, ctx_w, ctx);
        router_fused_kernel<<<256, 256, 0, stream>>>(x, gate_w, ctx, out, bp);
        aux_kernel<<<1, 1024, 0, stream>>>(bp, 256, out + 2 * 2 * T_TOKENS);
    }
}

// Round 6
// 240.925 us; speedup vs baseline: 1.3927x; 1.0203x over previous
//
#include <hip/hip_runtime.h>
#include <math.h>

// Problem constants: B=4, N=4096, C=2048, E=64, K=2
#define T_TOKENS 16384
#define C_DIM    2048
#define N_SEQ    4096
#define E_EXP    64
#define NSLICE   4        // split-K slices
#define KSLICE   512      // C_DIM / NSLICE
#define EPB      1024     // epilogue blocks
#define GN       131072   // gate elements per split part (64*2048)

typedef __attribute__((ext_vector_type(8))) short  short8;   // 8 bf16 = 4 VGPR
typedef __attribute__((ext_vector_type(4))) float  floatx4;

// ---- exact 3-way bf16 decomposition (truncation; residuals exact) ----------
__device__ __forceinline__ void splitv(float v, ushort& h, ushort& m, ushort& l) {
    unsigned u = __float_as_uint(v);
    h = (ushort)(u >> 16);
    float f1 = v - __uint_as_float(u & 0xffff0000u);       // exact
    unsigned u1 = __float_as_uint(f1);
    m = (ushort)(u1 >> 16);
    float f2 = f1 - __uint_as_float(u1 & 0xffff0000u);     // exact
    l = (ushort)(__float_as_uint(f2) >> 16);
}

__device__ __forceinline__ void splitpack8(const float4& a, const float4& b,
                                           short8& h, short8& m, short8& l) {
    ushort hh, mm, ll;
    splitv(a.x, hh, mm, ll); h[0] = hh; m[0] = mm; l[0] = ll;
    splitv(a.y, hh, mm, ll); h[1] = hh; m[1] = mm; l[1] = ll;
    splitv(a.z, hh, mm, ll); h[2] = hh; m[2] = mm; l[2] = ll;
    splitv(a.w, hh, mm, ll); h[3] = hh; m[3] = mm; l[3] = ll;
    splitv(b.x, hh, mm, ll); h[4] = hh; m[4] = mm; l[4] = ll;
    splitv(b.y, hh, mm, ll); h[5] = hh; m[5] = mm; l[5] = ll;
    splitv(b.z, hh, mm, ll); h[6] = hh; m[6] = mm; l[6] = ll;
    splitv(b.w, hh, mm, ll); h[7] = hh; m[7] = mm; l[7] = ll;
}

// RNE split for the one-time gate_w preprocessing
__device__ __forceinline__ void split3rne(float v, ushort& h, ushort& m, ushort& l) {
    unsigned u = __float_as_uint(v);
    unsigned r = (u + 0x7fffu + ((u >> 16) & 1u)) >> 16;
    h = (ushort)r;
    float e1 = v - __uint_as_float(r << 16);
    u = __float_as_uint(e1);
    r = (u + 0x7fffu + ((u >> 16) & 1u)) >> 16;
    m = (ushort)r;
    float e2 = e1 - __uint_as_float(r << 16);
    l = (ushort)(__float_as_uint(e2) >> 16);
}

// ---- shared ctx body: wave computes ctx[0..3][j] (bit-identical to R0) ----
__device__ __forceinline__ void ctx_body(
    int j, int lane, const float* __restrict__ rc,
    const float* __restrict__ ctx_w, float* __restrict__ ctx_out)
{
    const float4* wr = (const float4*)(ctx_w + (size_t)j * C_DIM);
    const float4* r0 = (const float4*)(rc);
    const float4* r1 = (const float4*)(rc + C_DIM);
    const float4* r2 = (const float4*)(rc + 2 * C_DIM);
    const float4* r3 = (const float4*)(rc + 3 * C_DIM);

    float s0 = 0.f, s1 = 0.f, s2 = 0.f, s3 = 0.f;
#pragma unroll
    for (int it = 0; it < 8; ++it) {
        float4 a  = wr[it * 64 + lane];
        float4 c0 = r0[it * 64 + lane];
        float4 c1 = r1[it * 64 + lane];
        float4 c2 = r2[it * 64 + lane];
        float4 c3 = r3[it * 64 + lane];
        s0 += a.x * c0.x + a.y * c0.y + a.z * c0.z + a.w * c0.w;
        s1 += a.x * c1.x + a.y * c1.y + a.z * c1.z + a.w * c1.w;
        s2 += a.x * c2.x + a.y * c2.y + a.z * c2.z + a.w * c2.w;
        s3 += a.x * c3.x + a.y * c3.y + a.z * c3.z + a.w * c3.w;
    }
#pragma unroll
    for (int off = 32; off; off >>= 1) {
        s0 += __shfl_xor(s0, off, 64);
        s1 += __shfl_xor(s1, off, 64);
        s2 += __shfl_xor(s2, off, 64);
        s3 += __shfl_xor(s3, off, 64);
    }
    if (lane == 0) {
        ctx_out[j]             = s0;
        ctx_out[C_DIM + j]     = s1;
        ctx_out[2 * C_DIM + j] = s2;
        ctx_out[3 * C_DIM + j] = s3;
    }
}

// ---------------------------------------------------------------------------
// Kernel 1: gsp split only (tiny; absorbs the post-poison L3 state first).
// ---------------------------------------------------------------------------
__global__ __launch_bounds__(256) void split_kernel(
    const float* __restrict__ gw, ushort* __restrict__ gsp)
{
    const int idx  = blockIdx.x * 256 + threadIdx.x;   // 0..131071
    const int j    = idx & 7;
    const int e    = (idx >> 3) & 63;
    const int koct = idx >> 9;
    float g = gw[(size_t)e * C_DIM + koct * 8 + j];
    ushort h, m, l;
    split3rne(g, h, m, l);
    gsp[idx]          = h;
    gsp[GN + idx]     = m;
    gsp[2 * GN + idx] = l;
}

// ---------------------------------------------------------------------------
// Kernel 2 (R6): blocks 0..511 = bf16x6 MFMA split-K GEMM with B staged in
// LDS (double-buffered, reg-staged ds_write_b128, one barrier per K-step).
// Mechanism: R2-R5 nulls traced to the 12 independent B vmem loads per
// K-step serializing at L2 latency (~300cy each) under tight regalloc —
// prefetch/hoist/launch-bounds couldn't force the compiler to pipeline them.
// LDS staging moves B to ds_read_b128 (~120cy, compiler-pipelined via
// lgkmcnt). XOR-swizzle (pre-swizzled SOURCE + swizzled READ, linear dest;
// involution verified) cuts the 8-way bank conflict to 4-way. B values and
// MFMA order bit-identical to R5 -> bit-identical P.
// Blocks 512..1023 = ctx (independent work, overlaps the HBM x-stream).
// ---------------------------------------------------------------------------
__global__ __launch_bounds__(256, 2) void gemm_ctx_kernel(
    const float* __restrict__ x, const ushort* __restrict__ gsp,
    const float* __restrict__ rc, const float* __restrict__ ctx_w,
    float* __restrict__ ctx_out, float* __restrict__ P)
{
    __shared__ ushort Bs[2][3][2048];        // 2 buf x 3 parts x 4KB = 24 KB

    if (blockIdx.x >= 128 * NSLICE) {
        const int lane = threadIdx.x & 63;
        const int j = (blockIdx.x - 128 * NSLICE) * 4 + (threadIdx.x >> 6); // 0..2047
        ctx_body(j, lane, rc, ctx_w, ctx_out);
        return;
    }

    const int tid   = threadIdx.x;
    const int wv    = tid >> 6;
    const int lane  = tid & 63;
    const int l15   = lane & 15;
    const int quad  = lane >> 4;
    const int tile  = blockIdx.x & 127;     // 128 tiles x 128 tokens
    const int slice = blockIdx.x >> 7;      // 0..3
    const int tw    = tile * 128 + wv * 32; // wave token base
    const int cbase = slice * KSLICE;

    floatx4 acc[2][4];
#pragma unroll
    for (int s = 0; s < 2; ++s)
#pragma unroll
        for (int nt = 0; nt < 4; ++nt) acc[s][nt] = (floatx4){0.f, 0.f, 0.f, 0.f};

    const float* xr0 = x + (size_t)(tw + l15) * C_DIM + cbase + quad * 8;
    const float* xr1 = xr0 + (size_t)16 * C_DIM;

    // Staging source (ushort units). Step ks covers kocts [ks*4, ks*4+4) of
    // this slice: 2048 contiguous ushorts (4KB) per part. Source pre-swizzle
    // (XOR low koct bits into the fragment-index bits) so that the LINEAR
    // LDS dest + swizzled READ reproduce the exact original B values:
    //   LDS[P] = G[P ^ ((P>>9)&3)<<3]  (involution within each 4KB part)
    const int swsrc = (tid * 8) ^ (((tid >> 6) & 3) << 3);
    const size_t stepbase0 = (size_t)(cbase >> 3) * 512;   // slice koct base

    // Read-side swizzled fragment offsets (per-lane constants):
    //   off(nt) = quad*512 + ((16*nt + l15) ^ quad) * 8
    int roff[4];
#pragma unroll
    for (int nt = 0; nt < 4; ++nt)
        roff[nt] = quad * 512 + (((16 * nt + l15) ^ quad) << 3);

    const int NKS = KSLICE / 32;            // 16 K=32 steps

    // ---- prologue: load B[0] and A[0] into registers ----
    short8 bn0 = *(const short8*)(gsp + 0 * (size_t)GN + stepbase0 + swsrc);
    short8 bn1 = *(const short8*)(gsp + 1 * (size_t)GN + stepbase0 + swsrc);
    short8 bn2 = *(const short8*)(gsp + 2 * (size_t)GN + stepbase0 + swsrc);
    float4 a00 = *(const float4*)(xr0);
    float4 a01 = *(const float4*)(xr0 + 4);
    float4 a10 = *(const float4*)(xr1);
    float4 a11 = *(const float4*)(xr1 + 4);

#pragma unroll 2
    for (int ks = 0; ks < NKS; ++ks) {
        // --- commit staged B[ks] registers to LDS buf[ks&1] (linear dest) ---
        ushort* bw = &Bs[ks & 1][0][0];
        *(short8*)(bw + 0 * 2048 + tid * 8) = bn0;
        *(short8*)(bw + 1 * 2048 + tid * 8) = bn1;
        *(short8*)(bw + 2 * 2048 + tid * 8) = bn2;

        // --- issue next-step B and A global loads (wrap on last; discarded) ---
        const int nk = (ks + 1 < NKS) ? (ks + 1) : 0;
        const size_t sb = stepbase0 + (size_t)nk * 2048;
        bn0 = *(const short8*)(gsp + 0 * (size_t)GN + sb + swsrc);
        bn1 = *(const short8*)(gsp + 1 * (size_t)GN + sb + swsrc);
        bn2 = *(const short8*)(gsp + 2 * (size_t)GN + sb + swsrc);
        float4 n00 = *(const float4*)(xr0 + nk * 32);
        float4 n01 = *(const float4*)(xr0 + nk * 32 + 4);
        float4 n10 = *(const float4*)(xr1 + nk * 32);
        float4 n11 = *(const float4*)(xr1 + nk * 32 + 4);

        // --- split current A while loads fly ---
        short8 ah0, am0, al0, ah1, am1, al1;
        splitpack8(a00, a01, ah0, am0, al0);
        splitpack8(a10, a11, ah1, am1, al1);

        __syncthreads();   // B[ks] LDS writes visible to all waves

        // --- inner MFMA loop: B from LDS (swizzled read) ---
        const ushort* br = &Bs[ks & 1][0][0];
#pragma unroll
        for (int nt = 0; nt < 4; ++nt) {
            short8 bh = *(const short8*)(br + 0 * 2048 + roff[nt]);
            short8 bm = *(const short8*)(br + 1 * 2048 + roff[nt]);
            short8 bl = *(const short8*)(br + 2 * 2048 + roff[nt]);
            acc[0][nt] = __builtin_amdgcn_mfma_f32_16x16x32_bf16(ah0, bh, acc[0][nt], 0, 0, 0);
            acc[0][nt] = __builtin_amdgcn_mfma_f32_16x16x32_bf16(ah0, bm, acc[0][nt], 0, 0, 0);
            acc[0][nt] = __builtin_amdgcn_mfma_f32_16x16x32_bf16(am0, bh, acc[0][nt], 0, 0, 0);
            acc[0][nt] = __builtin_amdgcn_mfma_f32_16x16x32_bf16(ah0, bl, acc[0][nt], 0, 0, 0);
            acc[0][nt] = __builtin_amdgcn_mfma_f32_16x16x32_bf16(al0, bh, acc[0][nt], 0, 0, 0);
            acc[0][nt] = __builtin_amdgcn_mfma_f32_16x16x32_bf16(am0, bm, acc[0][nt], 0, 0, 0);
            acc[1][nt] = __builtin_amdgcn_mfma_f32_16x16x32_bf16(ah1, bh, acc[1][nt], 0, 0, 0);
            acc[1][nt] = __builtin_amdgcn_mfma_f32_16x16x32_bf16(ah1, bm, acc[1][nt], 0, 0, 0);
            acc[1][nt] = __builtin_amdgcn_mfma_f32_16x16x32_bf16(am1, bh, acc[1][nt], 0, 0, 0);
            acc[1][nt] = __builtin_amdgcn_mfma_f32_16x16x32_bf16(ah1, bl, acc[1][nt], 0, 0, 0);
            acc[1][nt] = __builtin_amdgcn_mfma_f32_16x16x32_bf16(al1, bh, acc[1][nt], 0, 0, 0);
            acc[1][nt] = __builtin_amdgcn_mfma_f32_16x16x32_bf16(am1, bm, acc[1][nt], 0, 0, 0);
        }
        // no end barrier needed: next iteration writes the OTHER buffer,
        // whose last readers finished before the barrier we just passed.

        a00 = n00; a01 = n01; a10 = n10; a11 = n11;
    }

    // C/D layout (R6-verified): col=l15 (expert 16nt+l15), row=quad*4+r
    float* Ps = P + ((size_t)slice * T_TOKENS + tw) * E_EXP;
#pragma unroll
    for (int s = 0; s < 2; ++s)
#pragma unroll
        for (int nt = 0; nt < 4; ++nt)
#pragma unroll
            for (int r = 0; r < 4; ++r)
                Ps[(size_t)(s * 16 + quad * 4 + r) * E_EXP + 16 * nt + l15] =
                    acc[s][nt][r];
}

// ---------------------------------------------------------------------------
// Kernel 3: cl[b][e] = dot(ctx[b,:], gate_w[e,:]) — 64 blocks, tiny.
// ---------------------------------------------------------------------------
__global__ __launch_bounds__(256) void cl_kernel(
    const float* __restrict__ gw, const float* __restrict__ ctx,
    float* __restrict__ cl)
{
    const int lane = threadIdx.x & 63;
    const int pk   = blockIdx.x * 4 + (threadIdx.x >> 6);  // 0..255
    const int b    = pk >> 6;
    const int e    = pk & 63;
    const float4* wr = (const float4*)(gw + (size_t)e * C_DIM);
    const float4* cr = (const float4*)(ctx + (size_t)b * C_DIM);
    float s = 0.f;
#pragma unroll
    for (int it = 0; it < 8; ++it) {
        float4 a = wr[it * 64 + lane];
        float4 c = cr[it * 64 + lane];
        s += a.x * c.x + a.y * c.y + a.z * c.z + a.w * c.w;
    }
#pragma unroll
    for (int off = 32; off; off >>= 1) s += __shfl_xor(s, off, 64);
    if (lane == 0) cl[pk] = s;
}

// ---------------------------------------------------------------------------
// Kernel 4 (epilogue, proven): deterministic slice sum + cl[b][e], fused
// top-2+sumexp butterfly, per-block LDS reduce -> bp[block][128].
// ---------------------------------------------------------------------------
__global__ __launch_bounds__(256) void epilogue_kernel(
    const float* __restrict__ P, const float* __restrict__ cl,
    float* __restrict__ out, float* __restrict__ bp)
{
    __shared__ float red[4][128];

    const int tid  = threadIdx.x;
    const int wv   = tid >> 6;
    const int lane = tid & 63;
    const int t0   = blockIdx.x * (T_TOKENS / EPB);     // 16 tokens
    const float clv = cl[(t0 >> 12) * 64 + lane];       // batch = t0/4096

    float imp_acc = 0.f, cnt_acc = 0.f;

    for (int tt = 0; tt < 4; ++tt) {
        const int t = t0 + wv * 4 + tt;
        float v = clv;
#pragma unroll
        for (int s = 0; s < NSLICE; ++s)
            v += P[((size_t)s * T_TOKENS + t) * E_EXP + lane];

        const float p = expf(v);
        float v1 = v;  int i1 = lane;
        float v2 = -INFINITY; int i2 = 0x7fffffff;
        float s = p;
#pragma unroll
        for (int off = 32; off; off >>= 1) {
            float ov1 = __shfl_xor(v1, off, 64);
            int   oi1 = __shfl_xor(i1, off, 64);
            float ov2 = __shfl_xor(v2, off, 64);
            int   oi2 = __shfl_xor(i2, off, 64);
            s += __shfl_xor(s, off, 64);
            const bool aw = (ov1 < v1) || (ov1 == v1 && i1 < oi1);
            const float lv = aw ? ov1 : v1;  const int li = aw ? oi1 : i1;
            const float wv2 = aw ? v2 : ov2; const int wi = aw ? i2 : oi2;
            if (!aw) { v1 = ov1; i1 = oi1; }
            const bool sw = (wv2 < lv) || (wv2 == lv && li < wi);
            v2 = sw ? lv : wv2; i2 = sw ? li : wi;
        }

        imp_acc += p / s;
        if (lane == i1 || lane == i2) cnt_acc += 1.f;

        if (lane == 0) {
            const float e2 = expf(v2 - v1);
            out[2 * t]     = (float)i1;
            out[2 * t + 1] = (float)i2;
            out[2 * T_TOKENS + 2 * t]     = 1.f / (1.f + e2);
            out[2 * T_TOKENS + 2 * t + 1] = e2 / (1.f + e2);
        }
    }

    red[wv][lane]      = imp_acc;
    red[wv][64 + lane] = cnt_acc;
    __syncthreads();
    if (tid < 128) {
        float s = red[0][tid] + red[1][tid] + red[2][tid] + red[3][tid];
        bp[(size_t)blockIdx.x * 128 + tid] = s;
    }
}

// ---------------------------------------------------------------------------
// Kernel 5: parallel bp reduce -> aux loss (proven)
// ---------------------------------------------------------------------------
__global__ __launch_bounds__(1024) void aux_kernel(
    const float* __restrict__ bp, int nb, float* __restrict__ out_aux)
{
    __shared__ float4 red[32][32];
    const int tid = threadIdx.x;
    const int c4  = tid & 31;
    const int grp = tid >> 5;

    const float4* bp4 = (const float4*)bp;
    float4 s = make_float4(0.f, 0.f, 0.f, 0.f);
    for (int r = grp; r < nb; r += 32) {
        float4 v = bp4[(size_t)r * 32 + c4];
        s.x += v.x; s.y += v.y; s.z += v.z; s.w += v.w;
    }
    red[grp][c4] = s;
    __syncthreads();

    if (tid < 32) {
        float4 t = make_float4(0.f, 0.f, 0.f, 0.f);
#pragma unroll
        for (int g = 0; g < 32; ++g) {
            float4 v = red[g][tid];
            t.x += v.x; t.y += v.y; t.z += v.z; t.w += v.w;
        }
        red[0][tid] = t;
    }
    __syncthreads();

    if (tid < 16) {
        float4 a = red[0][tid];
        float4 b = red[0][tid + 16];
        float v = a.x * b.x + a.y * b.y + a.z * b.z + a.w * b.w;
#pragma unroll
        for (int off = 8; off; off >>= 1) v += __shfl_xor(v, off, 64);
        if (tid == 0)
            out_aux[0] = (float)E_EXP * v / ((float)T_TOKENS * (float)T_TOKENS);
    }
}

// ---------------------------------------------------------------------------
// Fallback path kernels (ws too small): ctx-only + fused fp32 + aux
// ---------------------------------------------------------------------------
__global__ __launch_bounds__(256) void ctx_only_kernel(
    const float* __restrict__ rc, const float* __restrict__ ctx_w,
    float* __restrict__ ctx_out)
{
    const int lane = threadIdx.x & 63;
    const int j    = blockIdx.x * 4 + (threadIdx.x >> 6);
    ctx_body(j, lane, rc, ctx_w, ctx_out);
}

#define TM    64
#define FKC   64
#define FLSTR 68
__global__ __launch_bounds__(256) void router_fused_kernel(
    const float* __restrict__ x, const float* __restrict__ gate_w,
    const float* __restrict__ ctx, float* __restrict__ out,
    float* __restrict__ bp)
{
    __shared__ float xs[TM][FLSTR];
    __shared__ float gs[E_EXP][FLSTR];
    __shared__ float ls[TM][FLSTR];
    __shared__ float red[4][128];

    const int tid = threadIdx.x;
    const int eg  = tid & 15;
    const int tg  = tid >> 4;
    const int t0  = blockIdx.x * TM;
    const int b   = t0 / N_SEQ;
    const int sr  = tid >> 4;
    const int scg = tid & 15;
    const float* ctx_row = ctx + (size_t)b * C_DIM;

    float4 acc[4][4];
#pragma unroll
    for (int i = 0; i < 4; ++i)
#pragma unroll
        for (int j = 0; j < 4; ++j) acc[i][j] = make_float4(0.f, 0.f, 0.f, 0.f);

    float4 px[4], pg[4], pc;
    auto prefetch = [&](int kc) {
        const int c0 = kc * FKC + scg * 4;
        pc = *(const float4*)(ctx_row + c0);
#pragma unroll
        for (int i = 0; i < 4; ++i) {
            px[i] = *(const float4*)(x + (size_t)(t0 + sr + 16 * i) * C_DIM + c0);
            pg[i] = *(const float4*)(gate_w + (size_t)(sr + 16 * i) * C_DIM + c0);
        }
    };

    prefetch(0);
    const int NCHUNK = C_DIM / FKC;
    for (int kc = 0; kc < NCHUNK; ++kc) {
        __syncthreads();
#pragma unroll
        for (int i = 0; i < 4; ++i) {
            float4 v = px[i];
            v.x += pc.x; v.y += pc.y; v.z += pc.z; v.w += pc.w;
            *(float4*)&xs[sr + 16 * i][scg * 4] = v;
            *(float4*)&gs[sr + 16 * i][scg * 4] = pg[i];
        }
        __syncthreads();
        if (kc + 1 < NCHUNK) prefetch(kc + 1);
#pragma unroll
        for (int cc = 0; cc < FKC; cc += 4) {
            float4 xv[4], gv[4];
#pragma unroll
            for (int i = 0; i < 4; ++i) xv[i] = *(const float4*)&xs[tg + 16 * i][cc];
#pragma unroll
            for (int j = 0; j < 4; ++j) gv[j] = *(const float4*)&gs[eg + 16 * j][cc];
#pragma unroll
            for (int i = 0; i < 4; ++i)
#pragma unroll
                for (int j = 0; j < 4; ++j) {
                    acc[i][j].x = fmaf(xv[i].x, gv[j].x, acc[i][j].x);
                    acc[i][j].y = fmaf(xv[i].y, gv[j].y, acc[i][j].y);
                    acc[i][j].z = fmaf(xv[i].z, gv[j].z, acc[i][j].z);
                    acc[i][j].w = fmaf(xv[i].w, gv[j].w, acc[i][j].w);
                }
        }
    }

    __syncthreads();
#pragma unroll
    for (int i = 0; i < 4; ++i)
#pragma unroll
        for (int j = 0; j < 4; ++j)
            ls[tg + 16 * i][eg + 16 * j] =
                (acc[i][j].x + acc[i][j].y) + (acc[i][j].z + acc[i][j].w);
    __syncthreads();

    const int wv   = tid >> 6;
    const int lane = tid & 63;
    float imp_acc = 0.f, cnt_acc = 0.f;

    for (int tt = 0; tt < 16; ++tt) {
        const int tokL = wv * 16 + tt;
        const float v = ls[tokL][lane];
        const float p = expf(v);
        float v1 = v;  int i1 = lane;
        float v2 = -INFINITY; int i2 = 0x7fffffff;
        float s = p;
#pragma unroll
        for (int off = 32; off; off >>= 1) {
            float ov1 = __shfl_xor(v1, off, 64);
            int   oi1 = __shfl_xor(i1, off, 64);
            float ov2 = __shfl_xor(v2, off, 64);
            int   oi2 = __shfl_xor(i2, off, 64);
            s += __shfl_xor(s, off, 64);
            const bool aw = (ov1 < v1) || (ov1 == v1 && i1 < oi1);
            const float lv = aw ? ov1 : v1;  const int li = aw ? oi1 : i1;
            const float wv2 = aw ? v2 : ov2; const int wi = aw ? i2 : oi2;
            if (!aw) { v1 = ov1; i1 = oi1; }
            const bool sw = (wv2 < lv) || (wv2 == lv && li < wi);
            v2 = sw ? lv : wv2; i2 = sw ? li : wi;
        }
        imp_acc += p / s;
        if (lane == i1 || lane == i2) cnt_acc += 1.f;
        if (lane == 0) {
            const int t = t0 + tokL;
            const float e2 = expf(v2 - v1);
            out[2 * t]     = (float)i1;
            out[2 * t + 1] = (float)i2;
            out[2 * T_TOKENS + 2 * t]     = 1.f / (1.f + e2);
            out[2 * T_TOKENS + 2 * t + 1] = e2 / (1.f + e2);
        }
    }

    red[wv][lane]      = imp_acc;
    red[wv][64 + lane] = cnt_acc;
    __syncthreads();
    if (tid < 128) {
        float s = red[0][tid] + red[1][tid] + red[2][tid] + red[3][tid];
        bp[(size_t)blockIdx.x * 128 + tid] = s;
    }
}

extern "C" void kernel_launch(void* const* d_in, const int* in_sizes, int n_in,
                              void* d_out, int out_size, void* d_ws, size_t ws_size,
                              hipStream_t stream)
{
    (void)in_sizes; (void)n_in; (void)out_size;
    const float* x      = (const float*)d_in[0];
    const float* rc     = (const float*)d_in[1];
    const float* gate_w = (const float*)d_in[2];
    const float* ctx_w  = (const float*)d_in[3];
    float* out = (float*)d_out;

    float*  ctx = (float*)d_ws;                            // 8192 f
    float*  cl  = ctx + 8192;                              // 256 f
    float*  bp  = cl + 256;                                // EPB*128 f
    float*  P   = bp + (size_t)EPB * 128;                  // NSLICE*T*E f
    ushort* gsp = (ushort*)(P + (size_t)NSLICE * T_TOKENS * E_EXP); // 3*GN us

    const size_t need =
        (8192 + 256 + (size_t)EPB * 128 + (size_t)NSLICE * T_TOKENS * E_EXP)
            * sizeof(float)
        + (size_t)3 * GN * sizeof(ushort);

    if (ws_size >= need) {
        split_kernel<<<512, 256, 0, stream>>>(gate_w, gsp);
        gemm_ctx_kernel<<<128 * NSLICE + 512, 256, 0, stream>>>(
            x, gsp, rc, ctx_w, ctx, P);
        cl_kernel<<<64, 256, 0, stream>>>(gate_w, ctx, cl);
        epilogue_kernel<<<EPB, 256, 0, stream>>>(P, cl, out, bp);
        aux_kernel<<<1, 1024, 0, stream>>>(bp, EPB, out + 2 * 2 * T_TOKENS);
    } else {
        ctx_only_kernel<<<512, 256, 0, stream>>>(rc, ctx_w, ctx);
        router_fused_kernel<<<256, 256, 0, stream>>>(x, gate_w, ctx, out, bp);
        aux_kernel<<<1, 1024, 0, stream>>>(bp, 256, out + 2 * 2 * T_TOKENS);
    }
}